// Round 15
// baseline (213.472 us; speedup 1.0000x reference)
//
#include <hip/hip_runtime.h>
#include <hip/hip_bf16.h>
#include <math.h>

#define DM 1024
#define DI 2048
#define DS 16
#define DTR 64
#define NB 2
#define LL 1024
#define MM (NB*LL)   // 2048
#define NC 32        // scan chunks
#define CL (LL/NC)   // 32
#define XSPLIT 8
#define XKC (DI/XSPLIT)  // 256

typedef unsigned short u16;
typedef __bf16 bf16x8 __attribute__((ext_vector_type(8)));
typedef float f32x4 __attribute__((ext_vector_type(4)));
typedef const __attribute__((address_space(1))) void gas_void;
typedef __attribute__((address_space(3))) void las_void;

__device__ __forceinline__ float sigmoidf_(float x){ return 1.f/(1.f+__expf(-x)); }
__device__ __forceinline__ float siluf_(float x){ return x*sigmoidf_(x); }
__device__ __forceinline__ float softplusf_(float x){ return fmaxf(x,0.f)+__logf(1.f+__expf(-fabsf(x))); }
__device__ __forceinline__ u16 f2b(float f){
  __hip_bfloat16 h = __float2bfloat16(f);
  return __builtin_bit_cast(unsigned short, h);
}
// P/F summaries live in the dead xb-half of xz (cols 0..2047 of each 4096-col row)
__device__ __forceinline__ size_t smap(size_t i){ return ((i>>11)<<12) + (i&2047); }
// CK-style: LDS generic VA low 32 bits = LDS offset; AS(3) ptr is 32-bit.
__device__ __forceinline__ void gld16(const u16* g, u16* l){
  __builtin_amdgcn_global_load_lds(
      reinterpret_cast<gas_void*>((unsigned long long)g),
      reinterpret_cast<las_void*>((unsigned)(unsigned long long)l), 16, 0, 0);
}

// ---------------- bf16 MFMA GEMM, 8-wave 128x128 tile ----------------
__global__ __launch_bounds__(512) void gemm_mfma_kern(
    const u16* __restrict__ A, const u16* __restrict__ Bt,
    float* __restrict__ C, int M, int N, int lda, int KS, int TN, int TM)
{
  __shared__ __attribute__((aligned(16))) u16 As[128*32];
  __shared__ __attribute__((aligned(16))) u16 Bs[128*32];
  const unsigned t = threadIdx.x;              // 0..511
  const unsigned l = t & 63;
  const unsigned w = t >> 6;                   // 0..7
  const unsigned wm = w >> 2, wn = w & 3;      // 2x4 wave grid, 64x32 each
  const int q8  = (int)gridDim.x >> 3;
  const int id2 = ((int)blockIdx.x & 7) * q8 + ((int)blockIdx.x >> 3);
  const int zz  = id2 / (TN*TM);
  const int rr  = id2 % (TN*TM);
  const int bm  = (rr / TN) * 128;
  const int bn  = (rr % TN) * 128;
  const int kbeg = zz * KS;
  const unsigned srow = t >> 2;                // 0..127
  const unsigned scol = (t & 3) * 8;
  f32x4 acc[4][2] = {};
  for (int k0 = kbeg; k0 < kbeg + KS; k0 += 32) {
    gld16(A  + (size_t)(bm + srow)*lda + k0 + scol, As + t*8);
    gld16(Bt + (size_t)(bn + srow)*lda + k0 + scol, Bs + t*8);
    __syncthreads();
    bf16x8 af[4], bfr[2];
    #pragma unroll
    for (int m = 0; m < 4; ++m)
      af[m] = *(const bf16x8*)(As + (wm*64 + m*16 + (l & 15))*32 + (l >> 4)*8);
    #pragma unroll
    for (int n = 0; n < 2; ++n)
      bfr[n] = *(const bf16x8*)(Bs + (wn*32 + n*16 + (l & 15))*32 + (l >> 4)*8);
    #pragma unroll
    for (int m = 0; m < 4; ++m)
      #pragma unroll
      for (int n = 0; n < 2; ++n)
        acc[m][n] = __builtin_amdgcn_mfma_f32_16x16x32_bf16(af[m], bfr[n], acc[m][n], 0, 0, 0);
    __syncthreads();
  }
  float* Cz = C + (size_t)zz*M*N;
  #pragma unroll
  for (int m = 0; m < 4; ++m) {
    #pragma unroll
    for (int n = 0; n < 2; ++n) {
      const int col = bn + wn*32 + n*16 + (l & 15);
      #pragma unroll
      for (int q = 0; q < 4; ++q) {
        const int row = bm + wm*64 + m*16 + (l >> 4)*4 + q;
        Cz[(size_t)row*N + col] = acc[m][n][q];
      }
    }
  }
}

// fixed-order sum of 4 split-K partials (deterministic)
__global__ __launch_bounds__(256) void reduce4_kern(
    const float* __restrict__ part, float* __restrict__ out)
{
  const size_t i = ((size_t)blockIdx.x*256 + threadIdx.x) * 4;
  float4 s = *(const float4*)(part + i);
  #pragma unroll
  for (int ks = 1; ks < 4; ++ks) {
    const float4 v = *(const float4*)(part + (size_t)ks*MM*DM + i);
    s.x+=v.x; s.y+=v.y; s.z+=v.z; s.w+=v.w;
  }
  *(float4*)(out + i) = s;
}

// ---------------- dt-proj (G3), fp32 one-pass ----------------
__global__ __launch_bounds__(256) void dtproj_kern(
    const float* __restrict__ params, const float* __restrict__ W_dt,
    const float* __restrict__ b_dt, float* __restrict__ delta)
{
  __shared__ __align__(16) float Ad[32][DTR];    // 8KB
  __shared__ __align__(16) float Wd[DTR][128];   // 32KB
  const int tid = threadIdx.x;
  const int m0 = (blockIdx.x >> 4) * 32;
  const int c0 = (blockIdx.x & 15) * 128;
  #pragma unroll
  for (int i = 0; i < 2; ++i) {
    const int fq = i*256 + tid;
    const int r = fq >> 4, q = fq & 15;
    *(float4*)&Ad[r][q*4] = *(const float4*)(params + (size_t)(m0+r)*96 + q*4);
  }
  #pragma unroll
  for (int i = 0; i < 8; ++i) {
    const int fq = i*256 + tid;
    const int r = fq >> 5, q = fq & 31;
    *(float4*)&Wd[r][q*4] = *(const float4*)(W_dt + (size_t)r*DI + c0 + q*4);
  }
  __syncthreads();
  const int tr = tid >> 5;
  const int tc = tid & 31;
  f32x4 acc[4] = {};
  #pragma unroll
  for (int k0 = 0; k0 < DTR; k0 += 4) {
    float4 a[4], wv[4];
    #pragma unroll
    for (int i = 0; i < 4; ++i) a[i] = *(const float4*)&Ad[tr*4+i][k0];
    #pragma unroll
    for (int j = 0; j < 4; ++j) wv[j] = *(const float4*)&Wd[k0+j][tc*4];
    #pragma unroll
    for (int i = 0; i < 4; ++i) {
      const float ai[4] = {a[i].x, a[i].y, a[i].z, a[i].w};
      #pragma unroll
      for (int j = 0; j < 4; ++j) {
        acc[i][0] = fmaf(ai[j], wv[j].x, acc[i][0]);
        acc[i][1] = fmaf(ai[j], wv[j].y, acc[i][1]);
        acc[i][2] = fmaf(ai[j], wv[j].z, acc[i][2]);
        acc[i][3] = fmaf(ai[j], wv[j].w, acc[i][3]);
      }
    }
  }
  const float4 b4 = *(const float4*)(b_dt + c0 + tc*4);
  #pragma unroll
  for (int i = 0; i < 4; ++i) {
    float4 o;
    o.x = softplusf_(acc[i][0] + b4.x);
    o.y = softplusf_(acc[i][1] + b4.y);
    o.z = softplusf_(acc[i][2] + b4.z);
    o.w = softplusf_(acc[i][3] + b4.w);
    *(float4*)(delta + (size_t)(m0 + tr*4 + i)*DI + c0 + tc*4) = o;
  }
}

// transpose + convert: in [R][C] f32 -> out [C][R] bf16. grid(C/32, R/32).
__global__ __launch_bounds__(256) void transpose_cvt_kern(
    const float* __restrict__ in, u16* __restrict__ out, int R, int C)
{
  __shared__ float tile[32][33];
  const int r0 = blockIdx.y*32, c0 = blockIdx.x*32;
  const int tr = threadIdx.x >> 3, tc4 = (threadIdx.x & 7) * 4;
  float4 v = *(const float4*)(in + (size_t)(r0+tr)*C + c0 + tc4);
  tile[tr][tc4+0] = v.x; tile[tr][tc4+1] = v.y;
  tile[tr][tc4+2] = v.z; tile[tr][tc4+3] = v.w;
  __syncthreads();
  ushort4 o;
  o.x = f2b(tile[tc4+0][tr]);
  o.y = f2b(tile[tc4+1][tr]);
  o.z = f2b(tile[tc4+2][tr]);
  o.w = f2b(tile[tc4+3][tr]);
  *(ushort4*)(out + (size_t)(c0+tr)*R + r0 + tc4) = o;
}

// strided convert: out[row][0..C) bf16 = in[row*ld .. +C). C mult of 4.
__global__ __launch_bounds__(256) void cvt_bf16_kern(
    const float* __restrict__ in, int ld, int C, u16* __restrict__ out, int rows)
{
  const int i = blockIdx.x*256 + threadIdx.x;
  if (i >= rows*(C/4)) return;
  const int row = i / (C/4);
  const int cq  = (i % (C/4)) * 4;
  float4 v = *(const float4*)(in + (size_t)row*ld + cq);
  ushort4 o; o.x=f2b(v.x); o.y=f2b(v.y); o.z=f2b(v.z); o.w=f2b(v.w);
  *(ushort4*)(out + (size_t)row*C + cq) = o;
}

// negA[d][n] = -exp(A_log[d][n])  (128KB table)
__global__ __launch_bounds__(256) void negA_kern(
    const float* __restrict__ A_log, float* __restrict__ negA)
{
  const int i = blockIdx.x*256 + threadIdx.x;   // over DI*DS/4
  float4 v = *(const float4*)(A_log + i*4);
  float4 o; o.x=-expf(v.x); o.y=-expf(v.y); o.z=-expf(v.z); o.w=-expf(v.w);
  *(float4*)(negA + i*4) = o;
}

// ---------------- x-proj (G2), K-split fp32 ----------------
__global__ __launch_bounds__(256) void xproj_part_kern(
    const float* __restrict__ u, const float* __restrict__ W_x,
    float* __restrict__ part)
{
  __shared__ __align__(16) float Uk[XKC][32];   // 32KB, k-major
  const int tid = threadIdx.x;
  const int m0 = (blockIdx.x & 63) * 32;
  const int ks = blockIdx.x >> 6;
  const int k0 = ks * XKC;
  #pragma unroll
  for (int i = 0; i < 8; ++i) {
    const int fq = i*256 + tid;                  // 2048 float4s
    const int r = fq & 31, kq = fq >> 5;
    const float4 v = *(const float4*)(u + (size_t)(m0+r)*DI + k0 + kq*4);
    Uk[kq*4+0][r] = v.x; Uk[kq*4+1][r] = v.y;
    Uk[kq*4+2][r] = v.z; Uk[kq*4+3][r] = v.w;
  }
  __syncthreads();
  const int r4 = tid >> 5;                       // rows r4*4..+3
  const int c  = tid & 31;
  f32x4 a0 = {}, a1 = {}, a2 = {};
  #pragma unroll 4
  for (int k = 0; k < XKC; ++k) {
    const float* w = W_x + (size_t)(k0+k)*96 + c;
    const float w0 = w[0], w1 = w[32], w2 = w[64];
    const float4 uv = *(const float4*)&Uk[k][r4*4];
    const float ur[4] = {uv.x, uv.y, uv.z, uv.w};
    #pragma unroll
    for (int i = 0; i < 4; ++i) {
      a0[i] = fmaf(ur[i], w0, a0[i]);
      a1[i] = fmaf(ur[i], w1, a1[i]);
      a2[i] = fmaf(ur[i], w2, a2[i]);
    }
  }
  #pragma unroll
  for (int i = 0; i < 4; ++i) {
    float* p = part + ((size_t)ks*MM + m0 + r4*4 + i)*96 + c;
    p[0] = a0[i]; p[32] = a1[i]; p[64] = a2[i];
  }
}

__global__ __launch_bounds__(256) void xproj_reduce_kern(
    const float* __restrict__ part, float* __restrict__ params)
{
  const int i = blockIdx.x*256 + threadIdx.x;
  float4 s = {0.f,0.f,0.f,0.f};
  #pragma unroll
  for (int ks = 0; ks < XSPLIT; ++ks) {
    float4 v = *(const float4*)(part + (size_t)ks*MM*96 + (size_t)i*4);
    s.x+=v.x; s.y+=v.y; s.z+=v.z; s.w+=v.w;
  }
  *(float4*)(params + (size_t)i*4) = s;
}

// Causal depthwise conv (D_CONV=4) + SiLU, float4 over d (4 channels/thread).
__global__ __launch_bounds__(256) void conv_silu_kern(
    const float* __restrict__ xz, const float* __restrict__ conv_w,
    const float* __restrict__ conv_b, float* __restrict__ u)
{
  const int idx = blockIdx.x * 256 + threadIdx.x;   // over MM*DI/4
  const int d4 = (idx & (DI/4 - 1)) * 4;
  const int ml = idx >> 9;
  const int l  = ml & (LL-1);
  const int base = ml - l;
  const float4 w0 = *(const float4*)(conv_w + (d4+0)*4);
  const float4 w1 = *(const float4*)(conv_w + (d4+1)*4);
  const float4 w2 = *(const float4*)(conv_w + (d4+2)*4);
  const float4 w3 = *(const float4*)(conv_w + (d4+3)*4);
  const float wt[4][4] = {{w0.x,w0.y,w0.z,w0.w},{w1.x,w1.y,w1.z,w1.w},
                          {w2.x,w2.y,w2.z,w2.w},{w3.x,w3.y,w3.z,w3.w}};
  float4 acc = *(const float4*)(conv_b + d4);
  #pragma unroll
  for (int j = 0; j < 4; ++j) {
    const int ls = l - 3 + j;
    if (ls >= 0) {
      const float4 v = *(const float4*)(xz + (size_t)(base + ls)*(2*DI) + d4);
      acc.x = fmaf(v.x, wt[0][j], acc.x);
      acc.y = fmaf(v.y, wt[1][j], acc.y);
      acc.z = fmaf(v.z, wt[2][j], acc.z);
      acc.w = fmaf(v.w, wt[3][j], acc.w);
    }
  }
  float4 o;
  o.x = siluf_(acc.x); o.y = siluf_(acc.y);
  o.z = siluf_(acc.z); o.w = siluf_(acc.w);
  *(float4*)(u + (size_t)idx*4) = o;
}

// ---- pass A: 2 lanes/channel, 8 states/lane; per-step partA (C-dot + D*u)
//      and cum written IN-PLACE over delta/u; chunk P/F for combine. ----
__global__ __launch_bounds__(256) void scan_passA_kern(
    float* __restrict__ delta, float* __restrict__ u,
    const float* __restrict__ params, const float* __restrict__ negA,
    const float* __restrict__ D_param,
    float* __restrict__ Pc, float* __restrict__ Fc)
{
  __shared__ __align__(16) float Bs[CL][DS];     // 2KB
  __shared__ __align__(16) float Cs[CL][DS];     // 2KB
  const int flat = blockIdx.x*256 + threadIdx.x;
  const int h  = flat & 1;                       // state half: n = h*8..h*8+7
  const int ch = flat >> 1;
  const int d = ch & (DI-1);
  const int c = (ch >> 11) & (NC-1);
  const int b = ch >> 16;
  const size_t lbase = (size_t)b*LL + (size_t)c*CL;
  {
    const int t = threadIdx.x;
    const int row = (t & 127) >> 2, col4 = (t & 3)*4;
    if (t < 128)
      *(float4*)&Bs[row][col4] = *(const float4*)(params + (lbase+row)*96 + DTR + col4);
    else
      *(float4*)&Cs[row][col4] = *(const float4*)(params + (lbase+row)*96 + DTR + DS + col4);
  }
  __syncthreads();
  float a[8];
  {
    const float4 a0 = *(const float4*)(negA + d*DS + h*8);
    const float4 a1 = *(const float4*)(negA + d*DS + h*8 + 4);
    a[0]=a0.x; a[1]=a0.y; a[2]=a0.z; a[3]=a0.w;
    a[4]=a1.x; a[5]=a1.y; a[6]=a1.z; a[7]=a1.w;
  }
  const float Dp = D_param[d];
  float* dl = delta + lbase*DI + d;
  float* uu = u     + lbase*DI + d;
  float s[8];
  #pragma unroll
  for (int n = 0; n < 8; ++n) s[n] = 0.f;
  float cum = 0.f;
  for (int l0 = 0; l0 < CL; l0 += 8) {
    float dtv[8], utv[8];
    #pragma unroll
    for (int j = 0; j < 8; ++j) {
      dtv[j] = dl[(size_t)(l0+j)*DI];
      utv[j] = uu[(size_t)(l0+j)*DI];
    }
    float pav[8], cumv[8];
    #pragma unroll
    for (int j = 0; j < 8; ++j) {
      const float dt = dtv[j];
      const float dtu = dt*utv[j];
      cum += dt; cumv[j] = cum;
      const float4 B0 = *(const float4*)&Bs[l0+j][h*8+0];
      const float4 B1 = *(const float4*)&Bs[l0+j][h*8+4];
      const float4 C0 = *(const float4*)&Cs[l0+j][h*8+0];
      const float4 C1 = *(const float4*)&Cs[l0+j][h*8+4];
      const float Bv[8] = {B0.x,B0.y,B0.z,B0.w, B1.x,B1.y,B1.z,B1.w};
      const float Cv[8] = {C0.x,C0.y,C0.z,C0.w, C1.x,C1.y,C1.z,C1.w};
      float part = 0.f;
      #pragma unroll
      for (int n = 0; n < 8; ++n) {
        s[n] = fmaf(__expf(dt*a[n]), s[n], dtu*Bv[n]);
        part = fmaf(s[n], Cv[n], part);
      }
      part += __shfl_xor(part, 1);
      pav[j] = part + Dp*utv[j];
    }
    if (h == 0) {
      #pragma unroll
      for (int j = 0; j < 8; ++j) {
        dl[(size_t)(l0+j)*DI] = pav[j];      // partA over delta
        uu[(size_t)(l0+j)*DI] = cumv[j];     // cum over u
      }
    }
  }
  const size_t base = (((size_t)(b*DI + d))*NC + c)*DS + h*8;
  float4 P0, P1;
  P0.x = __expf(cum*a[0]); P0.y = __expf(cum*a[1]);
  P0.z = __expf(cum*a[2]); P0.w = __expf(cum*a[3]);
  P1.x = __expf(cum*a[4]); P1.y = __expf(cum*a[5]);
  P1.z = __expf(cum*a[6]); P1.w = __expf(cum*a[7]);
  *(float4*)(Pc + smap(base))     = P0;
  *(float4*)(Pc + smap(base + 4)) = P1;
  *(float4*)(Fc + smap(base))     = make_float4(s[0],s[1],s[2],s[3]);
  *(float4*)(Fc + smap(base + 4)) = make_float4(s[4],s[5],s[6],s[7]);
}

// Combine: per (b,d,n), sequential over NC chunks. PS = Pc-in / Sinit-out.
__global__ __launch_bounds__(256) void scan_combine_kern(
    float* __restrict__ PS, const float* __restrict__ Fc)
{
  const int idx = blockIdx.x*256 + threadIdx.x;   // over NB*DI*DS
  const size_t base = (size_t)(idx >> 4) * (NC*DS) + (idx & 15);
  float s = 0.f;
  #pragma unroll
  for (int c = 0; c < NC; ++c) {
    const size_t a = smap(base + c*DS);
    const float P = PS[a], F = Fc[a];
    PS[a] = s;
    s = fmaf(P, s, F);
  }
}

// pass B: fully parallel finish. y = (partA + sum_n C[n]*exp(a_n*cum)*Sinit[n]) * silu(z)
__global__ __launch_bounds__(256) void scan_finish_kern(
    const float* __restrict__ partA, const float* __restrict__ cum,
    const float* __restrict__ params, const float* __restrict__ xz,
    const float* __restrict__ negA, const float* __restrict__ Sinit,
    u16* __restrict__ y16)
{
  const int idx = blockIdx.x*256 + threadIdx.x;   // over MM*DI
  const int d  = idx & (DI-1);
  const int ml = idx >> 11;
  const int l  = ml & (LL-1);
  const int b  = ml >> 10;
  const int c  = l >> 5;                          // CL=32
  const float pA = partA[idx];
  const float cm = cum[idx];
  const float z  = xz[(size_t)ml*(2*DI) + DI + d];
  const float* Cr = params + (size_t)ml*96 + DTR + DS;
  const size_t base = (((size_t)(b*DI + d))*NC + c)*DS;
  float acc = pA;
  #pragma unroll
  for (int i = 0; i < 4; ++i) {
    const float4 a4 = *(const float4*)(negA + d*DS + i*4);
    const float4 S4 = *(const float4*)(Sinit + smap(base + i*4));
    const float4 C4 = *(const float4*)(Cr + i*4);
    acc = fmaf(C4.x*__expf(a4.x*cm), S4.x, acc);
    acc = fmaf(C4.y*__expf(a4.y*cm), S4.y, acc);
    acc = fmaf(C4.z*__expf(a4.z*cm), S4.z, acc);
    acc = fmaf(C4.w*__expf(a4.w*cm), S4.w, acc);
  }
  y16[idx] = f2b(acc * siluf_(z));
}

extern "C" void kernel_launch(void* const* d_in, const int* in_sizes, int n_in,
                              void* d_out, int out_size, void* d_ws, size_t ws_size,
                              hipStream_t stream)
{
  const float* x      = (const float*)d_in[0];
  const float* W_in   = (const float*)d_in[1];
  const float* conv_w = (const float*)d_in[2];
  const float* conv_b = (const float*)d_in[3];
  const float* W_x    = (const float*)d_in[4];
  const float* W_dt   = (const float*)d_in[5];
  const float* b_dt   = (const float*)d_in[6];
  const float* W_out  = (const float*)d_in[7];
  const float* A_log  = (const float*)d_in[8];
  const float* D_par  = (const float*)d_in[9];
  float* out = (float*)d_out;

  float* xz     = (float*)d_ws;             // MM*4096 f32 (32MB)
  float* u      = xz + (size_t)MM*2*DI;     // MM*DI f32 (16MB); cum in-place
  float* params = u  + (size_t)MM*DI;       // MM*96 f32 (0.75MB)
  float* delta  = params + (size_t)MM*96;   // MM*DI f32 (16MB); partA in-place
  u16*  pool    = (u16*)(delta + (size_t)MM*DI);
  // G1 phase:
  u16* xb16 = pool;                          // 2048*1024 (4MB), dead after G1
  u16* Wi_t = (u16*)out;                     // 4096*1024 bf16 = 8MB, in d_out
  // post-G1 phase (reuses pool):
  u16* Wo_t   = pool;                        // 1024*2048 bf16 (4MB)
  u16* yb16   = pool + (size_t)DM*DI;        // 2048*2048 bf16 (8MB)
  // d_out staging (dead before the final reduce writes out):
  float* xpart = out;                        // [8][2048][96] f32 = 6.3MB (after G1)
  float* negA  = out + (size_t)1800*1024;    // 128KB table, tail of d_out (after G1)
  // scan summaries in the dead xb-half of xz (via smap)
  float* Pc = xz;                            // smap-addressed, becomes Sinit
  float* Fc = xz + (size_t)1024*4096;
  // G4 split-K partials in xz region (dead after scan): 4*MM*DM*4B = 32MB
  float* g4part = xz;

  dim3 blk(256);
  dim3 blk512(512);
  // convert x -> bf16; transpose-convert W_in -> [4096][1024] bf16 (in d_out)
  cvt_bf16_kern<<<(MM*DM/4 + 255)/256, blk, 0, stream>>>(x, DM, DM, xb16, MM);
  transpose_cvt_kern<<<dim3(2*DI/32, DM/32), blk, 0, stream>>>(W_in, Wi_t, DM, 2*DI);
  // G1: xz = x @ W_in   [2048 x 4096, K=1024]  (MFMA, 8-wave)
  gemm_mfma_kern<<<512, blk512, 0, stream>>>(xb16, Wi_t, xz, MM, 2*DI, DM, DM, 32, 16);
  // conv + silu -> u  (last reader of the xb-half of xz)
  conv_silu_kern<<<(MM*DI/4)/256, blk, 0, stream>>>(xz, conv_w, conv_b, u);
  // G2: params = u @ W_x  [2048 x 96, K=2048]  (fp32, K-split + reduce)
  xproj_part_kern<<<64*XSPLIT, blk, 0, stream>>>(u, W_x, xpart);
  xproj_reduce_kern<<<(MM*96/4)/256, blk, 0, stream>>>(xpart, params);
  // negA table (d_out tail, after Wi_t is dead)
  negA_kern<<<(DI*DS/4)/256, blk, 0, stream>>>(A_log, negA);
  // G3: delta = softplus(dlt @ W_dt + b_dt)  [2048 x 2048, K=64]  (fp32 one-pass)
  dtproj_kern<<<1024, blk, 0, stream>>>(params, W_dt, b_dt, delta);
  // scan: pass A (partA/cum in-place) -> combine -> parallel finish
  scan_passA_kern<<<(NB*NC*DI*2)/256, blk, 0, stream>>>(delta, u, params, negA, D_par, Pc, Fc);
  scan_combine_kern<<<(NB*DI*DS)/256, blk, 0, stream>>>(Pc, Fc);
  scan_finish_kern<<<(MM*DI)/256, blk, 0, stream>>>(delta, u, params, xz, negA, Pc, yb16);
  // G4: out = y @ W_out  [2048 x 1024, K=2048]  (MFMA, 8-wave, split-K=4 -> reduce)
  transpose_cvt_kern<<<dim3(DM/32, DI/32), blk, 0, stream>>>(W_out, Wo_t, DI, DM);
  gemm_mfma_kern<<<512, blk512, 0, stream>>>(yb16, Wo_t, g4part, MM, DM, DI, DI/4, 8, 16);
  reduce4_kern<<<(MM*DM/4)/256, blk, 0, stream>>>(g4part, out);
}

// Round 16
// 191.096 us; speedup vs baseline: 1.1171x; 1.1171x over previous
//
#include <hip/hip_runtime.h>
#include <hip/hip_bf16.h>
#include <math.h>

#define DM 1024
#define DI 2048
#define DS 16
#define DTR 64
#define NB 2
#define LL 1024
#define MM (NB*LL)   // 2048
#define NC 32        // scan chunks
#define CL (LL/NC)   // 32
#define XSPLIT 8
#define XKC (DI/XSPLIT)  // 256
#define LOG2E 1.442695040888963f

typedef unsigned short u16;
typedef __bf16 bf16x8 __attribute__((ext_vector_type(8)));
typedef float f32x4 __attribute__((ext_vector_type(4)));
typedef const __attribute__((address_space(1))) void gas_void;
typedef __attribute__((address_space(3))) void las_void;

__device__ __forceinline__ float sigmoidf_(float x){ return 1.f/(1.f+__expf(-x)); }
__device__ __forceinline__ float siluf_(float x){ return x*sigmoidf_(x); }
__device__ __forceinline__ float softplusf_(float x){ return fmaxf(x,0.f)+__logf(1.f+__expf(-fabsf(x))); }
__device__ __forceinline__ u16 f2b(float f){
  __hip_bfloat16 h = __float2bfloat16(f);
  return __builtin_bit_cast(unsigned short, h);
}
// P/F summaries live in the dead xb-half of xz (cols 0..2047 of each 4096-col row)
__device__ __forceinline__ size_t smap(size_t i){ return ((i>>11)<<12) + (i&2047); }
// CK-style: LDS generic VA low 32 bits = LDS offset; AS(3) ptr is 32-bit.
__device__ __forceinline__ void gld16(const u16* g, u16* l){
  __builtin_amdgcn_global_load_lds(
      reinterpret_cast<gas_void*>((unsigned long long)g),
      reinterpret_cast<las_void*>((unsigned)(unsigned long long)l), 16, 0, 0);
}

// ---------------- bf16 MFMA GEMM, 8-wave 128x128 tile ----------------
__global__ __launch_bounds__(512) void gemm_mfma_kern(
    const u16* __restrict__ A, const u16* __restrict__ Bt,
    float* __restrict__ C, int M, int N, int lda, int KS, int TN, int TM)
{
  __shared__ __attribute__((aligned(16))) u16 As[128*32];
  __shared__ __attribute__((aligned(16))) u16 Bs[128*32];
  const unsigned t = threadIdx.x;              // 0..511
  const unsigned l = t & 63;
  const unsigned w = t >> 6;                   // 0..7
  const unsigned wm = w >> 2, wn = w & 3;      // 2x4 wave grid, 64x32 each
  const int q8  = (int)gridDim.x >> 3;
  const int id2 = ((int)blockIdx.x & 7) * q8 + ((int)blockIdx.x >> 3);
  const int zz  = id2 / (TN*TM);
  const int rr  = id2 % (TN*TM);
  const int bm  = (rr / TN) * 128;
  const int bn  = (rr % TN) * 128;
  const int kbeg = zz * KS;
  const unsigned srow = t >> 2;                // 0..127
  const unsigned scol = (t & 3) * 8;
  f32x4 acc[4][2] = {};
  for (int k0 = kbeg; k0 < kbeg + KS; k0 += 32) {
    gld16(A  + (size_t)(bm + srow)*lda + k0 + scol, As + t*8);
    gld16(Bt + (size_t)(bn + srow)*lda + k0 + scol, Bs + t*8);
    __syncthreads();
    bf16x8 af[4], bfr[2];
    #pragma unroll
    for (int m = 0; m < 4; ++m)
      af[m] = *(const bf16x8*)(As + (wm*64 + m*16 + (l & 15))*32 + (l >> 4)*8);
    #pragma unroll
    for (int n = 0; n < 2; ++n)
      bfr[n] = *(const bf16x8*)(Bs + (wn*32 + n*16 + (l & 15))*32 + (l >> 4)*8);
    #pragma unroll
    for (int m = 0; m < 4; ++m)
      #pragma unroll
      for (int n = 0; n < 2; ++n)
        acc[m][n] = __builtin_amdgcn_mfma_f32_16x16x32_bf16(af[m], bfr[n], acc[m][n], 0, 0, 0);
    __syncthreads();
  }
  float* Cz = C + (size_t)zz*M*N;
  #pragma unroll
  for (int m = 0; m < 4; ++m) {
    #pragma unroll
    for (int n = 0; n < 2; ++n) {
      const int col = bn + wn*32 + n*16 + (l & 15);
      #pragma unroll
      for (int q = 0; q < 4; ++q) {
        const int row = bm + wm*64 + m*16 + (l >> 4)*4 + q;
        Cz[(size_t)row*N + col] = acc[m][n][q];
      }
    }
  }
}

// fixed-order sum of 4 split-K partials (deterministic)
__global__ __launch_bounds__(256) void reduce4_kern(
    const float* __restrict__ part, float* __restrict__ out)
{
  const size_t i = ((size_t)blockIdx.x*256 + threadIdx.x) * 4;
  float4 s = *(const float4*)(part + i);
  #pragma unroll
  for (int ks = 1; ks < 4; ++ks) {
    const float4 v = *(const float4*)(part + (size_t)ks*MM*DM + i);
    s.x+=v.x; s.y+=v.y; s.z+=v.z; s.w+=v.w;
  }
  *(float4*)(out + i) = s;
}

// ---------------- dt-proj (G3), fp32 one-pass ----------------
__global__ __launch_bounds__(256) void dtproj_kern(
    const float* __restrict__ params, const float* __restrict__ W_dt,
    const float* __restrict__ b_dt, float* __restrict__ delta)
{
  __shared__ __align__(16) float Ad[32][DTR];    // 8KB
  __shared__ __align__(16) float Wd[DTR][128];   // 32KB
  const int tid = threadIdx.x;
  const int m0 = (blockIdx.x >> 4) * 32;
  const int c0 = (blockIdx.x & 15) * 128;
  #pragma unroll
  for (int i = 0; i < 2; ++i) {
    const int fq = i*256 + tid;
    const int r = fq >> 4, q = fq & 15;
    *(float4*)&Ad[r][q*4] = *(const float4*)(params + (size_t)(m0+r)*96 + q*4);
  }
  #pragma unroll
  for (int i = 0; i < 8; ++i) {
    const int fq = i*256 + tid;
    const int r = fq >> 5, q = fq & 31;
    *(float4*)&Wd[r][q*4] = *(const float4*)(W_dt + (size_t)r*DI + c0 + q*4);
  }
  __syncthreads();
  const int tr = tid >> 5;
  const int tc = tid & 31;
  f32x4 acc[4] = {};
  #pragma unroll
  for (int k0 = 0; k0 < DTR; k0 += 4) {
    float4 a[4], wv[4];
    #pragma unroll
    for (int i = 0; i < 4; ++i) a[i] = *(const float4*)&Ad[tr*4+i][k0];
    #pragma unroll
    for (int j = 0; j < 4; ++j) wv[j] = *(const float4*)&Wd[k0+j][tc*4];
    #pragma unroll
    for (int i = 0; i < 4; ++i) {
      const float ai[4] = {a[i].x, a[i].y, a[i].z, a[i].w};
      #pragma unroll
      for (int j = 0; j < 4; ++j) {
        acc[i][0] = fmaf(ai[j], wv[j].x, acc[i][0]);
        acc[i][1] = fmaf(ai[j], wv[j].y, acc[i][1]);
        acc[i][2] = fmaf(ai[j], wv[j].z, acc[i][2]);
        acc[i][3] = fmaf(ai[j], wv[j].w, acc[i][3]);
      }
    }
  }
  const float4 b4 = *(const float4*)(b_dt + c0 + tc*4);
  #pragma unroll
  for (int i = 0; i < 4; ++i) {
    float4 o;
    o.x = softplusf_(acc[i][0] + b4.x);
    o.y = softplusf_(acc[i][1] + b4.y);
    o.z = softplusf_(acc[i][2] + b4.z);
    o.w = softplusf_(acc[i][3] + b4.w);
    *(float4*)(delta + (size_t)(m0 + tr*4 + i)*DI + c0 + tc*4) = o;
  }
}

// transpose + convert: in [R][C] f32 -> out [C][R] bf16. grid(C/32, R/32).
__global__ __launch_bounds__(256) void transpose_cvt_kern(
    const float* __restrict__ in, u16* __restrict__ out, int R, int C)
{
  __shared__ float tile[32][33];
  const int r0 = blockIdx.y*32, c0 = blockIdx.x*32;
  const int tr = threadIdx.x >> 3, tc4 = (threadIdx.x & 7) * 4;
  float4 v = *(const float4*)(in + (size_t)(r0+tr)*C + c0 + tc4);
  tile[tr][tc4+0] = v.x; tile[tr][tc4+1] = v.y;
  tile[tr][tc4+2] = v.z; tile[tr][tc4+3] = v.w;
  __syncthreads();
  ushort4 o;
  o.x = f2b(tile[tc4+0][tr]);
  o.y = f2b(tile[tc4+1][tr]);
  o.z = f2b(tile[tc4+2][tr]);
  o.w = f2b(tile[tc4+3][tr]);
  *(ushort4*)(out + (size_t)(c0+tr)*R + r0 + tc4) = o;
}

// strided convert: out[row][0..C) bf16 = in[row*ld .. +C). C mult of 4.
__global__ __launch_bounds__(256) void cvt_bf16_kern(
    const float* __restrict__ in, int ld, int C, u16* __restrict__ out, int rows)
{
  const int i = blockIdx.x*256 + threadIdx.x;
  if (i >= rows*(C/4)) return;
  const int row = i / (C/4);
  const int cq  = (i % (C/4)) * 4;
  float4 v = *(const float4*)(in + (size_t)row*ld + cq);
  ushort4 o; o.x=f2b(v.x); o.y=f2b(v.y); o.z=f2b(v.z); o.w=f2b(v.w);
  *(ushort4*)(out + (size_t)row*C + cq) = o;
}

// ---------------- x-proj (G2), K-split fp32 ----------------
__global__ __launch_bounds__(256) void xproj_part_kern(
    const float* __restrict__ u, const float* __restrict__ W_x,
    float* __restrict__ part)
{
  __shared__ __align__(16) float Uk[XKC][32];   // 32KB, k-major
  const int tid = threadIdx.x;
  const int m0 = (blockIdx.x & 63) * 32;
  const int ks = blockIdx.x >> 6;
  const int k0 = ks * XKC;
  #pragma unroll
  for (int i = 0; i < 8; ++i) {
    const int fq = i*256 + tid;                  // 2048 float4s
    const int r = fq & 31, kq = fq >> 5;
    const float4 v = *(const float4*)(u + (size_t)(m0+r)*DI + k0 + kq*4);
    Uk[kq*4+0][r] = v.x; Uk[kq*4+1][r] = v.y;
    Uk[kq*4+2][r] = v.z; Uk[kq*4+3][r] = v.w;
  }
  __syncthreads();
  const int r4 = tid >> 5;                       // rows r4*4..+3
  const int c  = tid & 31;
  f32x4 a0 = {}, a1 = {}, a2 = {};
  #pragma unroll 4
  for (int k = 0; k < XKC; ++k) {
    const float* w = W_x + (size_t)(k0+k)*96 + c;
    const float w0 = w[0], w1 = w[32], w2 = w[64];
    const float4 uv = *(const float4*)&Uk[k][r4*4];
    const float ur[4] = {uv.x, uv.y, uv.z, uv.w};
    #pragma unroll
    for (int i = 0; i < 4; ++i) {
      a0[i] = fmaf(ur[i], w0, a0[i]);
      a1[i] = fmaf(ur[i], w1, a1[i]);
      a2[i] = fmaf(ur[i], w2, a2[i]);
    }
  }
  #pragma unroll
  for (int i = 0; i < 4; ++i) {
    float* p = part + ((size_t)ks*MM + m0 + r4*4 + i)*96 + c;
    p[0] = a0[i]; p[32] = a1[i]; p[64] = a2[i];
  }
}

__global__ __launch_bounds__(256) void xproj_reduce_kern(
    const float* __restrict__ part, float* __restrict__ params)
{
  const int i = blockIdx.x*256 + threadIdx.x;
  float4 s = {0.f,0.f,0.f,0.f};
  #pragma unroll
  for (int ks = 0; ks < XSPLIT; ++ks) {
    float4 v = *(const float4*)(part + (size_t)ks*MM*96 + (size_t)i*4);
    s.x+=v.x; s.y+=v.y; s.z+=v.z; s.w+=v.w;
  }
  *(float4*)(params + (size_t)i*4) = s;
}

// Causal depthwise conv (D_CONV=4) + SiLU, float4 over d (4 channels/thread).
__global__ __launch_bounds__(256) void conv_silu_kern(
    const float* __restrict__ xz, const float* __restrict__ conv_w,
    const float* __restrict__ conv_b, float* __restrict__ u)
{
  const int idx = blockIdx.x * 256 + threadIdx.x;   // over MM*DI/4
  const int d4 = (idx & (DI/4 - 1)) * 4;
  const int ml = idx >> 9;
  const int l  = ml & (LL-1);
  const int base = ml - l;
  const float4 w0 = *(const float4*)(conv_w + (d4+0)*4);
  const float4 w1 = *(const float4*)(conv_w + (d4+1)*4);
  const float4 w2 = *(const float4*)(conv_w + (d4+2)*4);
  const float4 w3 = *(const float4*)(conv_w + (d4+3)*4);
  const float wt[4][4] = {{w0.x,w0.y,w0.z,w0.w},{w1.x,w1.y,w1.z,w1.w},
                          {w2.x,w2.y,w2.z,w2.w},{w3.x,w3.y,w3.z,w3.w}};
  float4 acc = *(const float4*)(conv_b + d4);
  #pragma unroll
  for (int j = 0; j < 4; ++j) {
    const int ls = l - 3 + j;
    if (ls >= 0) {
      const float4 v = *(const float4*)(xz + (size_t)(base + ls)*(2*DI) + d4);
      acc.x = fmaf(v.x, wt[0][j], acc.x);
      acc.y = fmaf(v.y, wt[1][j], acc.y);
      acc.z = fmaf(v.z, wt[2][j], acc.z);
      acc.w = fmaf(v.w, wt[3][j], acc.w);
    }
  }
  float4 o;
  o.x = siluf_(acc.x); o.y = siluf_(acc.y);
  o.z = siluf_(acc.z); o.w = siluf_(acc.w);
  *(float4*)(u + (size_t)idx*4) = o;
}

// ---- chunk-parallel selective scan: 2 lanes/channel, 8 states/lane ----
// grid 1024 blocks (4 waves/SIMD). 8-deep batched loads. B (and C) in LDS.
// a2[n] = -exp(A_log)*log2(e); exp2f maps directly to v_exp_f32.
__global__ __launch_bounds__(256) void scan_local_kern(
    const float* __restrict__ delta, const float* __restrict__ u,
    const float* __restrict__ params, const float* __restrict__ A_log,
    float* __restrict__ Pc, float* __restrict__ Fc)
{
  __shared__ __align__(16) float Bs[CL][DS];     // 2KB
  const int flat = blockIdx.x*256 + threadIdx.x;
  const int h  = flat & 1;                       // state half: n = h*8..h*8+7
  const int ch = flat >> 1;
  const int d = ch & (DI-1);
  const int c = (ch >> 11) & (NC-1);
  const int b = ch >> 16;
  const size_t lbase = (size_t)b*LL + (size_t)c*CL;
  if (threadIdx.x < CL*DS/4) {                   // 128 float4s
    const int row = threadIdx.x >> 2, col4 = (threadIdx.x & 3)*4;
    *(float4*)&Bs[row][col4] = *(const float4*)(params + (lbase+row)*96 + DTR + col4);
  }
  __syncthreads();
  float a2[8];
  #pragma unroll
  for (int i = 0; i < 2; ++i) {
    const float4 al = *(const float4*)(A_log + d*DS + h*8 + i*4);
    a2[i*4+0] = -expf(al.x)*LOG2E; a2[i*4+1] = -expf(al.y)*LOG2E;
    a2[i*4+2] = -expf(al.z)*LOG2E; a2[i*4+3] = -expf(al.w)*LOG2E;
  }
  const float* dl = delta + lbase*DI + d;
  const float* uu = u     + lbase*DI + d;
  float s[8];
  #pragma unroll
  for (int n = 0; n < 8; ++n) s[n] = 0.f;
  float dtsum = 0.f;
  for (int l0 = 0; l0 < CL; l0 += 8) {
    float dtv[8], utv[8];
    #pragma unroll
    for (int j = 0; j < 8; ++j) {
      dtv[j] = dl[(size_t)(l0+j)*DI];
      utv[j] = uu[(size_t)(l0+j)*DI];
    }
    #pragma unroll
    for (int j = 0; j < 8; ++j) {
      const float dt = dtv[j];
      const float dtu = dt*utv[j];
      dtsum += dt;
      const float4 B0 = *(const float4*)&Bs[l0+j][h*8+0];
      const float4 B1 = *(const float4*)&Bs[l0+j][h*8+4];
      const float Bv[8] = {B0.x,B0.y,B0.z,B0.w, B1.x,B1.y,B1.z,B1.w};
      #pragma unroll
      for (int n = 0; n < 8; ++n)
        s[n] = fmaf(exp2f(dt*a2[n]), s[n], dtu*Bv[n]);
    }
  }
  const size_t base = (((size_t)(b*DI + d))*NC + c)*DS + h*8;
  float4 P0, P1;
  P0.x = exp2f(dtsum*a2[0]); P0.y = exp2f(dtsum*a2[1]);
  P0.z = exp2f(dtsum*a2[2]); P0.w = exp2f(dtsum*a2[3]);
  P1.x = exp2f(dtsum*a2[4]); P1.y = exp2f(dtsum*a2[5]);
  P1.z = exp2f(dtsum*a2[6]); P1.w = exp2f(dtsum*a2[7]);
  *(float4*)(Pc + smap(base))     = P0;
  *(float4*)(Pc + smap(base + 4)) = P1;
  *(float4*)(Fc + smap(base))     = make_float4(s[0],s[1],s[2],s[3]);
  *(float4*)(Fc + smap(base + 4)) = make_float4(s[4],s[5],s[6],s[7]);
}

// Combine: per (b,d,n), sequential over NC chunks. PS = Pc-in / Sinit-out.
__global__ __launch_bounds__(256) void scan_combine_kern(
    float* __restrict__ PS, const float* __restrict__ Fc)
{
  const int idx = blockIdx.x*256 + threadIdx.x;   // over NB*DI*DS
  const size_t base = (size_t)(idx >> 4) * (NC*DS) + (idx & 15);
  float s = 0.f;
  #pragma unroll
  for (int c = 0; c < NC; ++c) {
    const size_t a = smap(base + c*DS);
    const float P = PS[a], F = Fc[a];
    PS[a] = s;
    s = fmaf(P, s, F);
  }
}

// Pass B: rescan chunk from Sinit; fused C-dot + D*u + silu(z) gate -> y bf16.
__global__ __launch_bounds__(256) void scan_apply_kern(
    const float* __restrict__ delta, const float* __restrict__ u,
    const float* __restrict__ params, const float* __restrict__ xz,
    const float* __restrict__ A_log, const float* __restrict__ D_param,
    const float* __restrict__ Sinit, u16* __restrict__ y16)
{
  __shared__ __align__(16) float Bs[CL][DS];     // 2KB
  __shared__ __align__(16) float Cs[CL][DS];     // 2KB
  const int flat = blockIdx.x*256 + threadIdx.x;
  const int h  = flat & 1;                       // state half
  const int ch = flat >> 1;
  const int d = ch & (DI-1);
  const int c = (ch >> 11) & (NC-1);
  const int b = ch >> 16;
  const size_t lbase = (size_t)b*LL + (size_t)c*CL;
  {
    const int t = threadIdx.x;
    const int row = (t & 127) >> 2, col4 = (t & 3)*4;
    if (t < 128)
      *(float4*)&Bs[row][col4] = *(const float4*)(params + (lbase+row)*96 + DTR + col4);
    else
      *(float4*)&Cs[row][col4] = *(const float4*)(params + (lbase+row)*96 + DTR + DS + col4);
  }
  __syncthreads();
  float a2[8];
  #pragma unroll
  for (int i = 0; i < 2; ++i) {
    const float4 al = *(const float4*)(A_log + d*DS + h*8 + i*4);
    a2[i*4+0] = -expf(al.x)*LOG2E; a2[i*4+1] = -expf(al.y)*LOG2E;
    a2[i*4+2] = -expf(al.z)*LOG2E; a2[i*4+3] = -expf(al.w)*LOG2E;
  }
  const float Dp = D_param[d];
  const float* dl = delta + lbase*DI + d;
  const float* uu = u     + lbase*DI + d;
  const float* zp = xz + lbase*(2*DI) + DI + d;
  u16* yo = y16 + lbase*DI + d;
  const size_t base = (((size_t)(b*DI + d))*NC + c)*DS + h*8;
  float s[8];
  {
    const float4 s0 = *(const float4*)(Sinit + smap(base));
    const float4 s1 = *(const float4*)(Sinit + smap(base + 4));
    s[0]=s0.x; s[1]=s0.y; s[2]=s0.z; s[3]=s0.w;
    s[4]=s1.x; s[5]=s1.y; s[6]=s1.z; s[7]=s1.w;
  }
  for (int l0 = 0; l0 < CL; l0 += 8) {
    float dtv[8], utv[8], zv[8];
    #pragma unroll
    for (int j = 0; j < 8; ++j) {
      dtv[j] = dl[(size_t)(l0+j)*DI];
      utv[j] = uu[(size_t)(l0+j)*DI];
      zv[j]  = zp[(size_t)(l0+j)*(2*DI)];
    }
    u16 yv[8];
    #pragma unroll
    for (int j = 0; j < 8; ++j) {
      const float dt = dtv[j];
      const float ut = utv[j];
      const float dtu = dt*ut;
      const float4 B0 = *(const float4*)&Bs[l0+j][h*8+0];
      const float4 B1 = *(const float4*)&Bs[l0+j][h*8+4];
      const float4 C0 = *(const float4*)&Cs[l0+j][h*8+0];
      const float4 C1 = *(const float4*)&Cs[l0+j][h*8+4];
      const float Bv[8] = {B0.x,B0.y,B0.z,B0.w, B1.x,B1.y,B1.z,B1.w};
      const float Cv[8] = {C0.x,C0.y,C0.z,C0.w, C1.x,C1.y,C1.z,C1.w};
      float part = 0.f;
      #pragma unroll
      for (int n = 0; n < 8; ++n) {
        s[n] = fmaf(exp2f(dt*a2[n]), s[n], dtu*Bv[n]);
        part = fmaf(s[n], Cv[n], part);
      }
      part += __shfl_xor(part, 1);               // pair-sum over state halves
      yv[j] = f2b((part + Dp*ut) * siluf_(zv[j]));
    }
    if (h == 0) {
      #pragma unroll
      for (int j = 0; j < 8; ++j)
        yo[(size_t)(l0+j)*DI] = yv[j];
    }
  }
}

extern "C" void kernel_launch(void* const* d_in, const int* in_sizes, int n_in,
                              void* d_out, int out_size, void* d_ws, size_t ws_size,
                              hipStream_t stream)
{
  const float* x      = (const float*)d_in[0];
  const float* W_in   = (const float*)d_in[1];
  const float* conv_w = (const float*)d_in[2];
  const float* conv_b = (const float*)d_in[3];
  const float* W_x    = (const float*)d_in[4];
  const float* W_dt   = (const float*)d_in[5];
  const float* b_dt   = (const float*)d_in[6];
  const float* W_out  = (const float*)d_in[7];
  const float* A_log  = (const float*)d_in[8];
  const float* D_par  = (const float*)d_in[9];
  float* out = (float*)d_out;

  float* xz     = (float*)d_ws;             // MM*4096 f32 (32MB)
  float* u      = xz + (size_t)MM*2*DI;     // MM*DI f32 (16MB)
  float* params = u  + (size_t)MM*DI;       // MM*96 f32 (0.75MB)
  float* delta  = params + (size_t)MM*96;   // MM*DI f32 (16MB)
  u16*  pool    = (u16*)(delta + (size_t)MM*DI);
  // G1 phase:
  u16* xb16 = pool;                          // 2048*1024 (4MB), dead after G1
  u16* Wi_t = (u16*)out;                     // 4096*1024 bf16 = 8MB, in d_out
  // post-G1 phase (reuses pool):
  u16* Wo_t   = pool;                        // 1024*2048 bf16 (4MB)
  u16* yb16   = pool + (size_t)DM*DI;        // 2048*2048 bf16 (8MB)
  // d_out staging (dead before the final reduce writes out):
  float* xpart = out;                        // [8][2048][96] f32 = 6.3MB (after G1)
  // scan summaries in the dead xb-half of xz (via smap)
  float* Pc = xz;                            // smap-addressed, becomes Sinit
  float* Fc = xz + (size_t)1024*4096;
  // G4 split-K partials in xz region (dead after scan_apply): 4*MM*DM*4B = 32MB
  float* g4part = xz;

  dim3 blk(256);
  dim3 blk512(512);
  // convert x -> bf16; transpose-convert W_in -> [4096][1024] bf16 (in d_out)
  cvt_bf16_kern<<<(MM*DM/4 + 255)/256, blk, 0, stream>>>(x, DM, DM, xb16, MM);
  transpose_cvt_kern<<<dim3(2*DI/32, DM/32), blk, 0, stream>>>(W_in, Wi_t, DM, 2*DI);
  // G1: xz = x @ W_in   [2048 x 4096, K=1024]  (MFMA, 8-wave)
  gemm_mfma_kern<<<512, blk512, 0, stream>>>(xb16, Wi_t, xz, MM, 2*DI, DM, DM, 32, 16);
  // conv + silu -> u  (last reader of the xb-half of xz)
  conv_silu_kern<<<(MM*DI/4)/256, blk, 0, stream>>>(xz, conv_w, conv_b, u);
  // G2: params = u @ W_x  [2048 x 96, K=2048]  (fp32, K-split + reduce)
  xproj_part_kern<<<64*XSPLIT, blk, 0, stream>>>(u, W_x, xpart);
  xproj_reduce_kern<<<(MM*96/4)/256, blk, 0, stream>>>(xpart, params);
  // G3: delta = softplus(dlt @ W_dt + b_dt)  [2048 x 2048, K=64]  (fp32 one-pass)
  dtproj_kern<<<1024, blk, 0, stream>>>(params, W_dt, b_dt, delta);
  // chunked scan, NC=32, 2 lanes/channel (y written as bf16 to yb16)
  scan_local_kern<<<(NB*NC*DI*2)/256, blk, 0, stream>>>(delta, u, params, A_log, Pc, Fc);
  scan_combine_kern<<<(NB*DI*DS)/256, blk, 0, stream>>>(Pc, Fc);
  scan_apply_kern<<<(NB*NC*DI*2)/256, blk, 0, stream>>>(delta, u, params, xz, A_log, D_par, Pc, yb16);
  // G4: out = y @ W_out  [2048 x 1024, K=2048]  (MFMA, 8-wave, split-K=4 -> reduce)
  transpose_cvt_kern<<<dim3(DM/32, DI/32), blk, 0, stream>>>(W_out, Wo_t, DI, DM);
  gemm_mfma_kern<<<512, blk512, 0, stream>>>(yb16, Wo_t, g4part, MM, DM, DI, DI/4, 8, 16);
  reduce4_kern<<<(MM*DM/4)/256, blk, 0, stream>>>(g4part, out);
}

// Round 18
// 181.096 us; speedup vs baseline: 1.1788x; 1.0552x over previous
//
#include <hip/hip_runtime.h>
#include <hip/hip_bf16.h>
#include <math.h>

#define DM 1024
#define DI 2048
#define DS 16
#define DTR 64
#define NB 2
#define LL 1024
#define MM (NB*LL)   // 2048
#define NC 32        // scan chunks
#define CL (LL/NC)   // 32
#define XSPLIT 8
#define XKC (DI/XSPLIT)  // 256

typedef unsigned short u16;
typedef __bf16 bf16x8 __attribute__((ext_vector_type(8)));
typedef float f32x4 __attribute__((ext_vector_type(4)));
typedef const __attribute__((address_space(1))) void gas_void;
typedef __attribute__((address_space(3))) void las_void;

__device__ __forceinline__ float sigmoidf_(float x){ return 1.f/(1.f+__expf(-x)); }
__device__ __forceinline__ float siluf_(float x){ return x*sigmoidf_(x); }
__device__ __forceinline__ float softplusf_(float x){ return fmaxf(x,0.f)+__logf(1.f+__expf(-fabsf(x))); }
__device__ __forceinline__ u16 f2b(float f){
  __hip_bfloat16 h = __float2bfloat16(f);
  return __builtin_bit_cast(unsigned short, h);
}
// P/F summaries live in the dead xb-half of xz (cols 0..2047 of each 4096-col row)
__device__ __forceinline__ size_t smap(size_t i){ return ((i>>11)<<12) + (i&2047); }
// CK-style: LDS generic VA low 32 bits = LDS offset; AS(3) ptr is 32-bit.
__device__ __forceinline__ void gld16(const u16* g, u16* l){
  __builtin_amdgcn_global_load_lds(
      reinterpret_cast<gas_void*>((unsigned long long)g),
      reinterpret_cast<las_void*>((unsigned)(unsigned long long)l), 16, 0, 0);
}

// ---------------- bf16 MFMA GEMM, 8-wave 128x128 tile ----------------
__global__ __launch_bounds__(512) void gemm_mfma_kern(
    const u16* __restrict__ A, const u16* __restrict__ Bt,
    float* __restrict__ C, int M, int N, int lda, int KS, int TN, int TM)
{
  __shared__ __attribute__((aligned(16))) u16 As[128*32];
  __shared__ __attribute__((aligned(16))) u16 Bs[128*32];
  const unsigned t = threadIdx.x;              // 0..511
  const unsigned l = t & 63;
  const unsigned w = t >> 6;                   // 0..7
  const unsigned wm = w >> 2, wn = w & 3;      // 2x4 wave grid, 64x32 each
  const int q8  = (int)gridDim.x >> 3;
  const int id2 = ((int)blockIdx.x & 7) * q8 + ((int)blockIdx.x >> 3);
  const int zz  = id2 / (TN*TM);
  const int rr  = id2 % (TN*TM);
  const int bm  = (rr / TN) * 128;
  const int bn  = (rr % TN) * 128;
  const int kbeg = zz * KS;
  const unsigned srow = t >> 2;                // 0..127
  const unsigned scol = (t & 3) * 8;
  f32x4 acc[4][2] = {};
  for (int k0 = kbeg; k0 < kbeg + KS; k0 += 32) {
    gld16(A  + (size_t)(bm + srow)*lda + k0 + scol, As + t*8);
    gld16(Bt + (size_t)(bn + srow)*lda + k0 + scol, Bs + t*8);
    __syncthreads();
    bf16x8 af[4], bfr[2];
    #pragma unroll
    for (int m = 0; m < 4; ++m)
      af[m] = *(const bf16x8*)(As + (wm*64 + m*16 + (l & 15))*32 + (l >> 4)*8);
    #pragma unroll
    for (int n = 0; n < 2; ++n)
      bfr[n] = *(const bf16x8*)(Bs + (wn*32 + n*16 + (l & 15))*32 + (l >> 4)*8);
    #pragma unroll
    for (int m = 0; m < 4; ++m)
      #pragma unroll
      for (int n = 0; n < 2; ++n)
        acc[m][n] = __builtin_amdgcn_mfma_f32_16x16x32_bf16(af[m], bfr[n], acc[m][n], 0, 0, 0);
    __syncthreads();
  }
  float* Cz = C + (size_t)zz*M*N;
  #pragma unroll
  for (int m = 0; m < 4; ++m) {
    #pragma unroll
    for (int n = 0; n < 2; ++n) {
      const int col = bn + wn*32 + n*16 + (l & 15);
      #pragma unroll
      for (int q = 0; q < 4; ++q) {
        const int row = bm + wm*64 + m*16 + (l >> 4)*4 + q;
        Cz[(size_t)row*N + col] = acc[m][n][q];
      }
    }
  }
}

// fixed-order sum of 4 split-K partials (deterministic)
__global__ __launch_bounds__(256) void reduce4_kern(
    const float* __restrict__ part, float* __restrict__ out)
{
  const size_t i = ((size_t)blockIdx.x*256 + threadIdx.x) * 4;
  float4 s = *(const float4*)(part + i);
  #pragma unroll
  for (int ks = 1; ks < 4; ++ks) {
    const float4 v = *(const float4*)(part + (size_t)ks*MM*DM + i);
    s.x+=v.x; s.y+=v.y; s.z+=v.z; s.w+=v.w;
  }
  *(float4*)(out + i) = s;
}

// ---------------- dt-proj (G3), fp32 one-pass ----------------
__global__ __launch_bounds__(256) void dtproj_kern(
    const float* __restrict__ params, const float* __restrict__ W_dt,
    const float* __restrict__ b_dt, float* __restrict__ delta)
{
  __shared__ __align__(16) float Ad[32][DTR];    // 8KB
  __shared__ __align__(16) float Wd[DTR][128];   // 32KB
  const int tid = threadIdx.x;
  const int m0 = (blockIdx.x >> 4) * 32;
  const int c0 = (blockIdx.x & 15) * 128;
  #pragma unroll
  for (int i = 0; i < 2; ++i) {
    const int fq = i*256 + tid;
    const int r = fq >> 4, q = fq & 15;
    *(float4*)&Ad[r][q*4] = *(const float4*)(params + (size_t)(m0+r)*96 + q*4);
  }
  #pragma unroll
  for (int i = 0; i < 8; ++i) {
    const int fq = i*256 + tid;
    const int r = fq >> 5, q = fq & 31;
    *(float4*)&Wd[r][q*4] = *(const float4*)(W_dt + (size_t)r*DI + c0 + q*4);
  }
  __syncthreads();
  const int tr = tid >> 5;
  const int tc = tid & 31;
  f32x4 acc[4] = {};
  #pragma unroll
  for (int k0 = 0; k0 < DTR; k0 += 4) {
    float4 a[4], wv[4];
    #pragma unroll
    for (int i = 0; i < 4; ++i) a[i] = *(const float4*)&Ad[tr*4+i][k0];
    #pragma unroll
    for (int j = 0; j < 4; ++j) wv[j] = *(const float4*)&Wd[k0+j][tc*4];
    #pragma unroll
    for (int i = 0; i < 4; ++i) {
      const float ai[4] = {a[i].x, a[i].y, a[i].z, a[i].w};
      #pragma unroll
      for (int j = 0; j < 4; ++j) {
        acc[i][0] = fmaf(ai[j], wv[j].x, acc[i][0]);
        acc[i][1] = fmaf(ai[j], wv[j].y, acc[i][1]);
        acc[i][2] = fmaf(ai[j], wv[j].z, acc[i][2]);
        acc[i][3] = fmaf(ai[j], wv[j].w, acc[i][3]);
      }
    }
  }
  const float4 b4 = *(const float4*)(b_dt + c0 + tc*4);
  #pragma unroll
  for (int i = 0; i < 4; ++i) {
    float4 o;
    o.x = softplusf_(acc[i][0] + b4.x);
    o.y = softplusf_(acc[i][1] + b4.y);
    o.z = softplusf_(acc[i][2] + b4.z);
    o.w = softplusf_(acc[i][3] + b4.w);
    *(float4*)(delta + (size_t)(m0 + tr*4 + i)*DI + c0 + tc*4) = o;
  }
}

// transpose + convert: in [R][C] f32 -> out [C][R] bf16. grid(C/32, R/32).
__global__ __launch_bounds__(256) void transpose_cvt_kern(
    const float* __restrict__ in, u16* __restrict__ out, int R, int C)
{
  __shared__ float tile[32][33];
  const int r0 = blockIdx.y*32, c0 = blockIdx.x*32;
  const int tr = threadIdx.x >> 3, tc4 = (threadIdx.x & 7) * 4;
  float4 v = *(const float4*)(in + (size_t)(r0+tr)*C + c0 + tc4);
  tile[tr][tc4+0] = v.x; tile[tr][tc4+1] = v.y;
  tile[tr][tc4+2] = v.z; tile[tr][tc4+3] = v.w;
  __syncthreads();
  ushort4 o;
  o.x = f2b(tile[tc4+0][tr]);
  o.y = f2b(tile[tc4+1][tr]);
  o.z = f2b(tile[tc4+2][tr]);
  o.w = f2b(tile[tc4+3][tr]);
  *(ushort4*)(out + (size_t)(c0+tr)*R + r0 + tc4) = o;
}

// strided convert: out[row][0..C) bf16 = in[row*ld .. +C). C mult of 4.
__global__ __launch_bounds__(256) void cvt_bf16_kern(
    const float* __restrict__ in, int ld, int C, u16* __restrict__ out, int rows)
{
  const int i = blockIdx.x*256 + threadIdx.x;
  if (i >= rows*(C/4)) return;
  const int row = i / (C/4);
  const int cq  = (i % (C/4)) * 4;
  float4 v = *(const float4*)(in + (size_t)row*ld + cq);
  ushort4 o; o.x=f2b(v.x); o.y=f2b(v.y); o.z=f2b(v.z); o.w=f2b(v.w);
  *(ushort4*)(out + (size_t)row*C + cq) = o;
}

// ---------------- x-proj (G2), K-split fp32 ----------------
__global__ __launch_bounds__(256) void xproj_part_kern(
    const float* __restrict__ u, const float* __restrict__ W_x,
    float* __restrict__ part)
{
  __shared__ __align__(16) float Uk[XKC][32];   // 32KB, k-major
  const int tid = threadIdx.x;
  const int m0 = (blockIdx.x & 63) * 32;
  const int ks = blockIdx.x >> 6;
  const int k0 = ks * XKC;
  #pragma unroll
  for (int i = 0; i < 8; ++i) {
    const int fq = i*256 + tid;                  // 2048 float4s
    const int r = fq & 31, kq = fq >> 5;
    const float4 v = *(const float4*)(u + (size_t)(m0+r)*DI + k0 + kq*4);
    Uk[kq*4+0][r] = v.x; Uk[kq*4+1][r] = v.y;
    Uk[kq*4+2][r] = v.z; Uk[kq*4+3][r] = v.w;
  }
  __syncthreads();
  const int r4 = tid >> 5;                       // rows r4*4..+3
  const int c  = tid & 31;
  f32x4 a0 = {}, a1 = {}, a2 = {};
  #pragma unroll 4
  for (int k = 0; k < XKC; ++k) {
    const float* w = W_x + (size_t)(k0+k)*96 + c;
    const float w0 = w[0], w1 = w[32], w2 = w[64];
    const float4 uv = *(const float4*)&Uk[k][r4*4];
    const float ur[4] = {uv.x, uv.y, uv.z, uv.w};
    #pragma unroll
    for (int i = 0; i < 4; ++i) {
      a0[i] = fmaf(ur[i], w0, a0[i]);
      a1[i] = fmaf(ur[i], w1, a1[i]);
      a2[i] = fmaf(ur[i], w2, a2[i]);
    }
  }
  #pragma unroll
  for (int i = 0; i < 4; ++i) {
    float* p = part + ((size_t)ks*MM + m0 + r4*4 + i)*96 + c;
    p[0] = a0[i]; p[32] = a1[i]; p[64] = a2[i];
  }
}

__global__ __launch_bounds__(256) void xproj_reduce_kern(
    const float* __restrict__ part, float* __restrict__ params)
{
  const int i = blockIdx.x*256 + threadIdx.x;
  float4 s = {0.f,0.f,0.f,0.f};
  #pragma unroll
  for (int ks = 0; ks < XSPLIT; ++ks) {
    float4 v = *(const float4*)(part + (size_t)ks*MM*96 + (size_t)i*4);
    s.x+=v.x; s.y+=v.y; s.z+=v.z; s.w+=v.w;
  }
  *(float4*)(params + (size_t)i*4) = s;
}

// Causal depthwise conv (D_CONV=4) + SiLU, float4 over d (4 channels/thread).
__global__ __launch_bounds__(256) void conv_silu_kern(
    const float* __restrict__ xz, const float* __restrict__ conv_w,
    const float* __restrict__ conv_b, float* __restrict__ u)
{
  const int idx = blockIdx.x * 256 + threadIdx.x;   // over MM*DI/4
  const int d4 = (idx & (DI/4 - 1)) * 4;
  const int ml = idx >> 9;
  const int l  = ml & (LL-1);
  const int base = ml - l;
  const float4 w0 = *(const float4*)(conv_w + (d4+0)*4);
  const float4 w1 = *(const float4*)(conv_w + (d4+1)*4);
  const float4 w2 = *(const float4*)(conv_w + (d4+2)*4);
  const float4 w3 = *(const float4*)(conv_w + (d4+3)*4);
  const float wt[4][4] = {{w0.x,w0.y,w0.z,w0.w},{w1.x,w1.y,w1.z,w1.w},
                          {w2.x,w2.y,w2.z,w2.w},{w3.x,w3.y,w3.z,w3.w}};
  float4 acc = *(const float4*)(conv_b + d4);
  #pragma unroll
  for (int j = 0; j < 4; ++j) {
    const int ls = l - 3 + j;
    if (ls >= 0) {
      const float4 v = *(const float4*)(xz + (size_t)(base + ls)*(2*DI) + d4);
      acc.x = fmaf(v.x, wt[0][j], acc.x);
      acc.y = fmaf(v.y, wt[1][j], acc.y);
      acc.z = fmaf(v.z, wt[2][j], acc.z);
      acc.w = fmaf(v.w, wt[3][j], acc.w);
    }
  }
  float4 o;
  o.x = siluf_(acc.x); o.y = siluf_(acc.y);
  o.z = siluf_(acc.z); o.w = siluf_(acc.w);
  *(float4*)(u + (size_t)idx*4) = o;
}

// ---- chunk-parallel selective scan: 2 lanes/channel, 8 states/lane ----
// grid 1024 blocks (4 waves/SIMD). 8-deep batched loads. B (and C) in LDS.
__global__ __launch_bounds__(256) void scan_local_kern(
    const float* __restrict__ delta, const float* __restrict__ u,
    const float* __restrict__ params, const float* __restrict__ A_log,
    float* __restrict__ Pc, float* __restrict__ Fc)
{
  __shared__ __align__(16) float Bs[CL][DS];     // 2KB
  const int flat = blockIdx.x*256 + threadIdx.x;
  const int h  = flat & 1;                       // state half: n = h*8..h*8+7
  const int ch = flat >> 1;
  const int d = ch & (DI-1);
  const int c = (ch >> 11) & (NC-1);
  const int b = ch >> 16;
  const size_t lbase = (size_t)b*LL + (size_t)c*CL;
  if (threadIdx.x < CL*DS/4) {                   // 128 float4s
    const int row = threadIdx.x >> 2, col4 = (threadIdx.x & 3)*4;
    *(float4*)&Bs[row][col4] = *(const float4*)(params + (lbase+row)*96 + DTR + col4);
  }
  __syncthreads();
  float a[8];
  #pragma unroll
  for (int i = 0; i < 2; ++i) {
    const float4 al = *(const float4*)(A_log + d*DS + h*8 + i*4);
    a[i*4+0] = -expf(al.x); a[i*4+1] = -expf(al.y);
    a[i*4+2] = -expf(al.z); a[i*4+3] = -expf(al.w);
  }
  const float* dl = delta + lbase*DI + d;
  const float* uu = u     + lbase*DI + d;
  float s[8];
  #pragma unroll
  for (int n = 0; n < 8; ++n) s[n] = 0.f;
  float dtsum = 0.f;
  for (int l0 = 0; l0 < CL; l0 += 8) {
    float dtv[8], utv[8];
    #pragma unroll
    for (int j = 0; j < 8; ++j) {
      dtv[j] = dl[(size_t)(l0+j)*DI];
      utv[j] = uu[(size_t)(l0+j)*DI];
    }
    #pragma unroll
    for (int j = 0; j < 8; ++j) {
      const float dt = dtv[j];
      const float dtu = dt*utv[j];
      dtsum += dt;
      const float4 B0 = *(const float4*)&Bs[l0+j][h*8+0];
      const float4 B1 = *(const float4*)&Bs[l0+j][h*8+4];
      const float Bv[8] = {B0.x,B0.y,B0.z,B0.w, B1.x,B1.y,B1.z,B1.w};
      #pragma unroll
      for (int n = 0; n < 8; ++n)
        s[n] = fmaf(__expf(dt*a[n]), s[n], dtu*Bv[n]);
    }
  }
  const size_t base = (((size_t)(b*DI + d))*NC + c)*DS + h*8;
  float4 P0, P1;
  P0.x = __expf(dtsum*a[0]); P0.y = __expf(dtsum*a[1]);
  P0.z = __expf(dtsum*a[2]); P0.w = __expf(dtsum*a[3]);
  P1.x = __expf(dtsum*a[4]); P1.y = __expf(dtsum*a[5]);
  P1.z = __expf(dtsum*a[6]); P1.w = __expf(dtsum*a[7]);
  *(float4*)(Pc + smap(base))     = P0;
  *(float4*)(Pc + smap(base + 4)) = P1;
  *(float4*)(Fc + smap(base))     = make_float4(s[0],s[1],s[2],s[3]);
  *(float4*)(Fc + smap(base + 4)) = make_float4(s[4],s[5],s[6],s[7]);
}

// Combine: per (b,d,n), sequential over NC chunks. PS = Pc-in / Sinit-out.
__global__ __launch_bounds__(256) void scan_combine_kern(
    float* __restrict__ PS, const float* __restrict__ Fc)
{
  const int idx = blockIdx.x*256 + threadIdx.x;   // over NB*DI*DS
  const size_t base = (size_t)(idx >> 4) * (NC*DS) + (idx & 15);
  float s = 0.f;
  #pragma unroll
  for (int c = 0; c < NC; ++c) {
    const size_t a = smap(base + c*DS);
    const float P = PS[a], F = Fc[a];
    PS[a] = s;
    s = fmaf(P, s, F);
  }
}

// Pass B: rescan chunk from Sinit; fused C-dot + D*u + silu(z) gate -> y bf16.
__global__ __launch_bounds__(256) void scan_apply_kern(
    const float* __restrict__ delta, const float* __restrict__ u,
    const float* __restrict__ params, const float* __restrict__ xz,
    const float* __restrict__ A_log, const float* __restrict__ D_param,
    const float* __restrict__ Sinit, u16* __restrict__ y16)
{
  __shared__ __align__(16) float Bs[CL][DS];     // 2KB
  __shared__ __align__(16) float Cs[CL][DS];     // 2KB
  const int flat = blockIdx.x*256 + threadIdx.x;
  const int h  = flat & 1;                       // state half
  const int ch = flat >> 1;
  const int d = ch & (DI-1);
  const int c = (ch >> 11) & (NC-1);
  const int b = ch >> 16;
  const size_t lbase = (size_t)b*LL + (size_t)c*CL;
  {
    const int t = threadIdx.x;
    const int row = (t & 127) >> 2, col4 = (t & 3)*4;
    if (t < 128)
      *(float4*)&Bs[row][col4] = *(const float4*)(params + (lbase+row)*96 + DTR + col4);
    else
      *(float4*)&Cs[row][col4] = *(const float4*)(params + (lbase+row)*96 + DTR + DS + col4);
  }
  __syncthreads();
  float a[8];
  #pragma unroll
  for (int i = 0; i < 2; ++i) {
    const float4 al = *(const float4*)(A_log + d*DS + h*8 + i*4);
    a[i*4+0] = -expf(al.x); a[i*4+1] = -expf(al.y);
    a[i*4+2] = -expf(al.z); a[i*4+3] = -expf(al.w);
  }
  const float Dp = D_param[d];
  const float* dl = delta + lbase*DI + d;
  const float* uu = u     + lbase*DI + d;
  const float* zp = xz + lbase*(2*DI) + DI + d;
  u16* yo = y16 + lbase*DI + d;
  const size_t base = (((size_t)(b*DI + d))*NC + c)*DS + h*8;
  float s[8];
  {
    const float4 s0 = *(const float4*)(Sinit + smap(base));
    const float4 s1 = *(const float4*)(Sinit + smap(base + 4));
    s[0]=s0.x; s[1]=s0.y; s[2]=s0.z; s[3]=s0.w;
    s[4]=s1.x; s[5]=s1.y; s[6]=s1.z; s[7]=s1.w;
  }
  for (int l0 = 0; l0 < CL; l0 += 8) {
    float dtv[8], utv[8], zv[8];
    #pragma unroll
    for (int j = 0; j < 8; ++j) {
      dtv[j] = dl[(size_t)(l0+j)*DI];
      utv[j] = uu[(size_t)(l0+j)*DI];
      zv[j]  = zp[(size_t)(l0+j)*(2*DI)];
    }
    u16 yv[8];
    #pragma unroll
    for (int j = 0; j < 8; ++j) {
      const float dt = dtv[j];
      const float ut = utv[j];
      const float dtu = dt*ut;
      const float4 B0 = *(const float4*)&Bs[l0+j][h*8+0];
      const float4 B1 = *(const float4*)&Bs[l0+j][h*8+4];
      const float4 C0 = *(const float4*)&Cs[l0+j][h*8+0];
      const float4 C1 = *(const float4*)&Cs[l0+j][h*8+4];
      const float Bv[8] = {B0.x,B0.y,B0.z,B0.w, B1.x,B1.y,B1.z,B1.w};
      const float Cv[8] = {C0.x,C0.y,C0.z,C0.w, C1.x,C1.y,C1.z,C1.w};
      float part = 0.f;
      #pragma unroll
      for (int n = 0; n < 8; ++n) {
        s[n] = fmaf(__expf(dt*a[n]), s[n], dtu*Bv[n]);
        part = fmaf(s[n], Cv[n], part);
      }
      part += __shfl_xor(part, 1);               // pair-sum over state halves
      yv[j] = f2b((part + Dp*ut) * siluf_(zv[j]));
    }
    if (h == 0) {
      #pragma unroll
      for (int j = 0; j < 8; ++j)
        yo[(size_t)(l0+j)*DI] = yv[j];
    }
  }
}

extern "C" void kernel_launch(void* const* d_in, const int* in_sizes, int n_in,
                              void* d_out, int out_size, void* d_ws, size_t ws_size,
                              hipStream_t stream)
{
  const float* x      = (const float*)d_in[0];
  const float* W_in   = (const float*)d_in[1];
  const float* conv_w = (const float*)d_in[2];
  const float* conv_b = (const float*)d_in[3];
  const float* W_x    = (const float*)d_in[4];
  const float* W_dt   = (const float*)d_in[5];
  const float* b_dt   = (const float*)d_in[6];
  const float* W_out  = (const float*)d_in[7];
  const float* A_log  = (const float*)d_in[8];
  const float* D_par  = (const float*)d_in[9];
  float* out = (float*)d_out;

  float* xz     = (float*)d_ws;             // MM*4096 f32 (32MB)
  float* u      = xz + (size_t)MM*2*DI;     // MM*DI f32 (16MB)
  float* params = u  + (size_t)MM*DI;       // MM*96 f32 (0.75MB)
  float* delta  = params + (size_t)MM*96;   // MM*DI f32 (16MB)
  u16*  pool    = (u16*)(delta + (size_t)MM*DI);
  // G1 phase:
  u16* xb16 = pool;                          // 2048*1024 (4MB), dead after G1
  u16* Wi_t = (u16*)out;                     // 4096*1024 bf16 = 8MB, in d_out
  // post-G1 phase (reuses pool):
  u16* Wo_t   = pool;                        // 1024*2048 bf16 (4MB)
  u16* yb16   = pool + (size_t)DM*DI;        // 2048*2048 bf16 (8MB)
  // d_out staging (dead before the final reduce writes out):
  float* xpart = out;                        // [8][2048][96] f32 = 6.3MB (after G1)
  // scan summaries in the dead xb-half of xz (via smap)
  float* Pc = xz;                            // smap-addressed, becomes Sinit
  float* Fc = xz + (size_t)1024*4096;
  // G4 split-K partials in xz region (dead after scan_apply): 4*MM*DM*4B = 32MB
  float* g4part = xz;

  dim3 blk(256);
  dim3 blk512(512);
  // convert x -> bf16; transpose-convert W_in -> [4096][1024] bf16 (in d_out)
  cvt_bf16_kern<<<(MM*DM/4 + 255)/256, blk, 0, stream>>>(x, DM, DM, xb16, MM);
  transpose_cvt_kern<<<dim3(2*DI/32, DM/32), blk, 0, stream>>>(W_in, Wi_t, DM, 2*DI);
  // G1: xz = x @ W_in   [2048 x 4096, K=1024]  (MFMA, 8-wave)
  gemm_mfma_kern<<<512, blk512, 0, stream>>>(xb16, Wi_t, xz, MM, 2*DI, DM, DM, 32, 16);
  // conv + silu -> u  (last reader of the xb-half of xz)
  conv_silu_kern<<<(MM*DI/4)/256, blk, 0, stream>>>(xz, conv_w, conv_b, u);
  // G2: params = u @ W_x  [2048 x 96, K=2048]  (fp32, K-split + reduce)
  xproj_part_kern<<<64*XSPLIT, blk, 0, stream>>>(u, W_x, xpart);
  xproj_reduce_kern<<<(MM*96/4)/256, blk, 0, stream>>>(xpart, params);
  // G3: delta = softplus(dlt @ W_dt + b_dt)  [2048 x 2048, K=64]  (fp32 one-pass)
  dtproj_kern<<<1024, blk, 0, stream>>>(params, W_dt, b_dt, delta);
  // chunked scan, NC=32, 2 lanes/channel (y written as bf16 to yb16)
  scan_local_kern<<<(NB*NC*DI*2)/256, blk, 0, stream>>>(delta, u, params, A_log, Pc, Fc);
  scan_combine_kern<<<(NB*DI*DS)/256, blk, 0, stream>>>(Pc, Fc);
  scan_apply_kern<<<(NB*NC*DI*2)/256, blk, 0, stream>>>(delta, u, params, xz, A_log, D_par, Pc, yb16);
  // G4: out = y @ W_out  [2048 x 1024, K=2048]  (MFMA, 8-wave, split-K=4 -> reduce)
  transpose_cvt_kern<<<dim3(DM/32, DI/32), blk, 0, stream>>>(W_out, Wo_t, DI, DM);
  gemm_mfma_kern<<<512, blk512, 0, stream>>>(yb16, Wo_t, g4part, MM, DM, DI, DI/4, 8, 16);
  reduce4_kern<<<(MM*DM/4)/256, blk, 0, stream>>>(g4part, out);
}

// Round 19
// 180.940 us; speedup vs baseline: 1.1798x; 1.0009x over previous
//
#include <hip/hip_runtime.h>
#include <hip/hip_bf16.h>
#include <math.h>

#define DM 1024
#define DI 2048
#define DS 16
#define DTR 64
#define NB 2
#define LL 1024
#define MM (NB*LL)   // 2048
#define NC 64        // scan chunks
#define CL (LL/NC)   // 16
#define XSPLIT 8
#define XKC (DI/XSPLIT)  // 256

typedef unsigned short u16;
typedef __bf16 bf16x8 __attribute__((ext_vector_type(8)));
typedef float f32x4 __attribute__((ext_vector_type(4)));
typedef const __attribute__((address_space(1))) void gas_void;
typedef __attribute__((address_space(3))) void las_void;

__device__ __forceinline__ float sigmoidf_(float x){ return 1.f/(1.f+__expf(-x)); }
__device__ __forceinline__ float siluf_(float x){ return x*sigmoidf_(x); }
__device__ __forceinline__ float softplusf_(float x){ return fmaxf(x,0.f)+__logf(1.f+__expf(-fabsf(x))); }
__device__ __forceinline__ u16 f2b(float f){
  __hip_bfloat16 h = __float2bfloat16(f);
  return __builtin_bit_cast(unsigned short, h);
}
// CK-style: LDS generic VA low 32 bits = LDS offset; AS(3) ptr is 32-bit.
__device__ __forceinline__ void gld16(const u16* g, u16* l){
  __builtin_amdgcn_global_load_lds(
      reinterpret_cast<gas_void*>((unsigned long long)g),
      reinterpret_cast<las_void*>((unsigned)(unsigned long long)l), 16, 0, 0);
}

// ---------------- bf16 MFMA GEMM, 8-wave 128x128 tile ----------------
__global__ __launch_bounds__(512) void gemm_mfma_kern(
    const u16* __restrict__ A, const u16* __restrict__ Bt,
    float* __restrict__ C, int M, int N, int lda, int KS, int TN, int TM)
{
  __shared__ __attribute__((aligned(16))) u16 As[128*32];
  __shared__ __attribute__((aligned(16))) u16 Bs[128*32];
  const unsigned t = threadIdx.x;              // 0..511
  const unsigned l = t & 63;
  const unsigned w = t >> 6;                   // 0..7
  const unsigned wm = w >> 2, wn = w & 3;      // 2x4 wave grid, 64x32 each
  const int q8  = (int)gridDim.x >> 3;
  const int id2 = ((int)blockIdx.x & 7) * q8 + ((int)blockIdx.x >> 3);
  const int zz  = id2 / (TN*TM);
  const int rr  = id2 % (TN*TM);
  const int bm  = (rr / TN) * 128;
  const int bn  = (rr % TN) * 128;
  const int kbeg = zz * KS;
  const unsigned srow = t >> 2;                // 0..127
  const unsigned scol = (t & 3) * 8;
  f32x4 acc[4][2] = {};
  for (int k0 = kbeg; k0 < kbeg + KS; k0 += 32) {
    gld16(A  + (size_t)(bm + srow)*lda + k0 + scol, As + t*8);
    gld16(Bt + (size_t)(bn + srow)*lda + k0 + scol, Bs + t*8);
    __syncthreads();
    bf16x8 af[4], bfr[2];
    #pragma unroll
    for (int m = 0; m < 4; ++m)
      af[m] = *(const bf16x8*)(As + (wm*64 + m*16 + (l & 15))*32 + (l >> 4)*8);
    #pragma unroll
    for (int n = 0; n < 2; ++n)
      bfr[n] = *(const bf16x8*)(Bs + (wn*32 + n*16 + (l & 15))*32 + (l >> 4)*8);
    #pragma unroll
    for (int m = 0; m < 4; ++m)
      #pragma unroll
      for (int n = 0; n < 2; ++n)
        acc[m][n] = __builtin_amdgcn_mfma_f32_16x16x32_bf16(af[m], bfr[n], acc[m][n], 0, 0, 0);
    __syncthreads();
  }
  float* Cz = C + (size_t)zz*M*N;
  #pragma unroll
  for (int m = 0; m < 4; ++m) {
    #pragma unroll
    for (int n = 0; n < 2; ++n) {
      const int col = bn + wn*32 + n*16 + (l & 15);
      #pragma unroll
      for (int q = 0; q < 4; ++q) {
        const int row = bm + wm*64 + m*16 + (l >> 4)*4 + q;
        Cz[(size_t)row*N + col] = acc[m][n][q];
      }
    }
  }
}

// fixed-order sum of 4 split-K partials (deterministic)
__global__ __launch_bounds__(256) void reduce4_kern(
    const float* __restrict__ part, float* __restrict__ out)
{
  const size_t i = ((size_t)blockIdx.x*256 + threadIdx.x) * 4;
  float4 s = *(const float4*)(part + i);
  #pragma unroll
  for (int ks = 1; ks < 4; ++ks) {
    const float4 v = *(const float4*)(part + (size_t)ks*MM*DM + i);
    s.x+=v.x; s.y+=v.y; s.z+=v.z; s.w+=v.w;
  }
  *(float4*)(out + i) = s;
}

// ---------------- dt-proj (G3), fp32 one-pass ----------------
__global__ __launch_bounds__(256) void dtproj_kern(
    const float* __restrict__ params, const float* __restrict__ W_dt,
    const float* __restrict__ b_dt, float* __restrict__ delta)
{
  __shared__ __align__(16) float Ad[32][DTR];    // 8KB
  __shared__ __align__(16) float Wd[DTR][128];   // 32KB
  const int tid = threadIdx.x;
  const int m0 = (blockIdx.x >> 4) * 32;
  const int c0 = (blockIdx.x & 15) * 128;
  #pragma unroll
  for (int i = 0; i < 2; ++i) {
    const int fq = i*256 + tid;
    const int r = fq >> 4, q = fq & 15;
    *(float4*)&Ad[r][q*4] = *(const float4*)(params + (size_t)(m0+r)*96 + q*4);
  }
  #pragma unroll
  for (int i = 0; i < 8; ++i) {
    const int fq = i*256 + tid;
    const int r = fq >> 5, q = fq & 31;
    *(float4*)&Wd[r][q*4] = *(const float4*)(W_dt + (size_t)r*DI + c0 + q*4);
  }
  __syncthreads();
  const int tr = tid >> 5;
  const int tc = tid & 31;
  f32x4 acc[4] = {};
  #pragma unroll
  for (int k0 = 0; k0 < DTR; k0 += 4) {
    float4 a[4], wv[4];
    #pragma unroll
    for (int i = 0; i < 4; ++i) a[i] = *(const float4*)&Ad[tr*4+i][k0];
    #pragma unroll
    for (int j = 0; j < 4; ++j) wv[j] = *(const float4*)&Wd[k0+j][tc*4];
    #pragma unroll
    for (int i = 0; i < 4; ++i) {
      const float ai[4] = {a[i].x, a[i].y, a[i].z, a[i].w};
      #pragma unroll
      for (int j = 0; j < 4; ++j) {
        acc[i][0] = fmaf(ai[j], wv[j].x, acc[i][0]);
        acc[i][1] = fmaf(ai[j], wv[j].y, acc[i][1]);
        acc[i][2] = fmaf(ai[j], wv[j].z, acc[i][2]);
        acc[i][3] = fmaf(ai[j], wv[j].w, acc[i][3]);
      }
    }
  }
  const float4 b4 = *(const float4*)(b_dt + c0 + tc*4);
  #pragma unroll
  for (int i = 0; i < 4; ++i) {
    float4 o;
    o.x = softplusf_(acc[i][0] + b4.x);
    o.y = softplusf_(acc[i][1] + b4.y);
    o.z = softplusf_(acc[i][2] + b4.z);
    o.w = softplusf_(acc[i][3] + b4.w);
    *(float4*)(delta + (size_t)(m0 + tr*4 + i)*DI + c0 + tc*4) = o;
  }
}

// transpose + convert: in [R][C] f32 -> out [C][R] bf16. grid(C/32, R/32).
__global__ __launch_bounds__(256) void transpose_cvt_kern(
    const float* __restrict__ in, u16* __restrict__ out, int R, int C)
{
  __shared__ float tile[32][33];
  const int r0 = blockIdx.y*32, c0 = blockIdx.x*32;
  const int tr = threadIdx.x >> 3, tc4 = (threadIdx.x & 7) * 4;
  float4 v = *(const float4*)(in + (size_t)(r0+tr)*C + c0 + tc4);
  tile[tr][tc4+0] = v.x; tile[tr][tc4+1] = v.y;
  tile[tr][tc4+2] = v.z; tile[tr][tc4+3] = v.w;
  __syncthreads();
  ushort4 o;
  o.x = f2b(tile[tc4+0][tr]);
  o.y = f2b(tile[tc4+1][tr]);
  o.z = f2b(tile[tc4+2][tr]);
  o.w = f2b(tile[tc4+3][tr]);
  *(ushort4*)(out + (size_t)(c0+tr)*R + r0 + tc4) = o;
}

// strided convert: out[row][0..C) bf16 = in[row*ld .. +C). C mult of 4.
__global__ __launch_bounds__(256) void cvt_bf16_kern(
    const float* __restrict__ in, int ld, int C, u16* __restrict__ out, int rows)
{
  const int i = blockIdx.x*256 + threadIdx.x;
  if (i >= rows*(C/4)) return;
  const int row = i / (C/4);
  const int cq  = (i % (C/4)) * 4;
  float4 v = *(const float4*)(in + (size_t)row*ld + cq);
  ushort4 o; o.x=f2b(v.x); o.y=f2b(v.y); o.z=f2b(v.z); o.w=f2b(v.w);
  *(ushort4*)(out + (size_t)row*C + cq) = o;
}

// ---------------- x-proj (G2), K-split fp32 ----------------
__global__ __launch_bounds__(256) void xproj_part_kern(
    const float* __restrict__ u, const float* __restrict__ W_x,
    float* __restrict__ part)
{
  __shared__ __align__(16) float Uk[XKC][32];   // 32KB, k-major
  const int tid = threadIdx.x;
  const int m0 = (blockIdx.x & 63) * 32;
  const int ks = blockIdx.x >> 6;
  const int k0 = ks * XKC;
  #pragma unroll
  for (int i = 0; i < 8; ++i) {
    const int fq = i*256 + tid;                  // 2048 float4s
    const int r = fq & 31, kq = fq >> 5;
    const float4 v = *(const float4*)(u + (size_t)(m0+r)*DI + k0 + kq*4);
    Uk[kq*4+0][r] = v.x; Uk[kq*4+1][r] = v.y;
    Uk[kq*4+2][r] = v.z; Uk[kq*4+3][r] = v.w;
  }
  __syncthreads();
  const int r4 = tid >> 5;                       // rows r4*4..+3
  const int c  = tid & 31;
  f32x4 a0 = {}, a1 = {}, a2 = {};
  #pragma unroll 4
  for (int k = 0; k < XKC; ++k) {
    const float* w = W_x + (size_t)(k0+k)*96 + c;
    const float w0 = w[0], w1 = w[32], w2 = w[64];
    const float4 uv = *(const float4*)&Uk[k][r4*4];
    const float ur[4] = {uv.x, uv.y, uv.z, uv.w};
    #pragma unroll
    for (int i = 0; i < 4; ++i) {
      a0[i] = fmaf(ur[i], w0, a0[i]);
      a1[i] = fmaf(ur[i], w1, a1[i]);
      a2[i] = fmaf(ur[i], w2, a2[i]);
    }
  }
  #pragma unroll
  for (int i = 0; i < 4; ++i) {
    float* p = part + ((size_t)ks*MM + m0 + r4*4 + i)*96 + c;
    p[0] = a0[i]; p[32] = a1[i]; p[64] = a2[i];
  }
}

__global__ __launch_bounds__(256) void xproj_reduce_kern(
    const float* __restrict__ part, float* __restrict__ params)
{
  const int i = blockIdx.x*256 + threadIdx.x;
  float4 s = {0.f,0.f,0.f,0.f};
  #pragma unroll
  for (int ks = 0; ks < XSPLIT; ++ks) {
    float4 v = *(const float4*)(part + (size_t)ks*MM*96 + (size_t)i*4);
    s.x+=v.x; s.y+=v.y; s.z+=v.z; s.w+=v.w;
  }
  *(float4*)(params + (size_t)i*4) = s;
}

// Causal depthwise conv (D_CONV=4) + SiLU, float4 over d (4 channels/thread).
__global__ __launch_bounds__(256) void conv_silu_kern(
    const float* __restrict__ xz, const float* __restrict__ conv_w,
    const float* __restrict__ conv_b, float* __restrict__ u)
{
  const int idx = blockIdx.x * 256 + threadIdx.x;   // over MM*DI/4
  const int d4 = (idx & (DI/4 - 1)) * 4;
  const int ml = idx >> 9;
  const int l  = ml & (LL-1);
  const int base = ml - l;
  const float4 w0 = *(const float4*)(conv_w + (d4+0)*4);
  const float4 w1 = *(const float4*)(conv_w + (d4+1)*4);
  const float4 w2 = *(const float4*)(conv_w + (d4+2)*4);
  const float4 w3 = *(const float4*)(conv_w + (d4+3)*4);
  const float wt[4][4] = {{w0.x,w0.y,w0.z,w0.w},{w1.x,w1.y,w1.z,w1.w},
                          {w2.x,w2.y,w2.z,w2.w},{w3.x,w3.y,w3.z,w3.w}};
  float4 acc = *(const float4*)(conv_b + d4);
  #pragma unroll
  for (int j = 0; j < 4; ++j) {
    const int ls = l - 3 + j;
    if (ls >= 0) {
      const float4 v = *(const float4*)(xz + (size_t)(base + ls)*(2*DI) + d4);
      acc.x = fmaf(v.x, wt[0][j], acc.x);
      acc.y = fmaf(v.y, wt[1][j], acc.y);
      acc.z = fmaf(v.z, wt[2][j], acc.z);
      acc.w = fmaf(v.w, wt[3][j], acc.w);
    }
  }
  float4 o;
  o.x = siluf_(acc.x); o.y = siluf_(acc.y);
  o.z = siluf_(acc.z); o.w = siluf_(acc.w);
  *(float4*)(u + (size_t)idx*4) = o;
}

// ---- chunk-parallel selective scan: 2 lanes/channel, 8 states/lane, NC=64 ----
// grid 2048 blocks (8 waves/SIMD). 8-deep batched loads. B (and C) in LDS.
// P/F in dedicated workspace buffers (contiguous, no aliasing).
__global__ __launch_bounds__(256) void scan_local_kern(
    const float* __restrict__ delta, const float* __restrict__ u,
    const float* __restrict__ params, const float* __restrict__ A_log,
    float* __restrict__ Pc, float* __restrict__ Fc)
{
  __shared__ __align__(16) float Bs[CL][DS];     // 1KB
  const int flat = blockIdx.x*256 + threadIdx.x;
  const int h  = flat & 1;                       // state half: n = h*8..h*8+7
  const int ch = flat >> 1;
  const int d = ch & (DI-1);
  const int c = (ch >> 11) & (NC-1);
  const int b = ch >> 17;
  const size_t lbase = (size_t)b*LL + (size_t)c*CL;
  if (threadIdx.x < CL*DS/4) {                   // 64 float4s
    const int row = threadIdx.x >> 2, col4 = (threadIdx.x & 3)*4;
    *(float4*)&Bs[row][col4] = *(const float4*)(params + (lbase+row)*96 + DTR + col4);
  }
  __syncthreads();
  float a[8];
  #pragma unroll
  for (int i = 0; i < 2; ++i) {
    const float4 al = *(const float4*)(A_log + d*DS + h*8 + i*4);
    a[i*4+0] = -expf(al.x); a[i*4+1] = -expf(al.y);
    a[i*4+2] = -expf(al.z); a[i*4+3] = -expf(al.w);
  }
  const float* dl = delta + lbase*DI + d;
  const float* uu = u     + lbase*DI + d;
  float s[8];
  #pragma unroll
  for (int n = 0; n < 8; ++n) s[n] = 0.f;
  float dtsum = 0.f;
  for (int l0 = 0; l0 < CL; l0 += 8) {
    float dtv[8], utv[8];
    #pragma unroll
    for (int j = 0; j < 8; ++j) {
      dtv[j] = dl[(size_t)(l0+j)*DI];
      utv[j] = uu[(size_t)(l0+j)*DI];
    }
    #pragma unroll
    for (int j = 0; j < 8; ++j) {
      const float dt = dtv[j];
      const float dtu = dt*utv[j];
      dtsum += dt;
      const float4 B0 = *(const float4*)&Bs[l0+j][h*8+0];
      const float4 B1 = *(const float4*)&Bs[l0+j][h*8+4];
      const float Bv[8] = {B0.x,B0.y,B0.z,B0.w, B1.x,B1.y,B1.z,B1.w};
      #pragma unroll
      for (int n = 0; n < 8; ++n)
        s[n] = fmaf(__expf(dt*a[n]), s[n], dtu*Bv[n]);
    }
  }
  const size_t base = (((size_t)(b*DI + d))*NC + c)*DS + h*8;
  float4 P0, P1;
  P0.x = __expf(dtsum*a[0]); P0.y = __expf(dtsum*a[1]);
  P0.z = __expf(dtsum*a[2]); P0.w = __expf(dtsum*a[3]);
  P1.x = __expf(dtsum*a[4]); P1.y = __expf(dtsum*a[5]);
  P1.z = __expf(dtsum*a[6]); P1.w = __expf(dtsum*a[7]);
  *(float4*)(Pc + base)     = P0;
  *(float4*)(Pc + base + 4) = P1;
  *(float4*)(Fc + base)     = make_float4(s[0],s[1],s[2],s[3]);
  *(float4*)(Fc + base + 4) = make_float4(s[4],s[5],s[6],s[7]);
}

// Combine: per (b,d,n), sequential over NC chunks. PS = Pc-in / Sinit-out.
__global__ __launch_bounds__(256) void scan_combine_kern(
    float* __restrict__ PS, const float* __restrict__ Fc)
{
  const int idx = blockIdx.x*256 + threadIdx.x;   // over NB*DI*DS
  const size_t base = (size_t)(idx >> 4) * (NC*DS) + (idx & 15);
  float s = 0.f;
  #pragma unroll
  for (int c = 0; c < NC; ++c) {
    const size_t a = base + (size_t)c*DS;
    const float P = PS[a], F = Fc[a];
    PS[a] = s;
    s = fmaf(P, s, F);
  }
}

// Pass B: rescan chunk from Sinit; fused C-dot + D*u + silu(z) gate -> y bf16.
__global__ __launch_bounds__(256) void scan_apply_kern(
    const float* __restrict__ delta, const float* __restrict__ u,
    const float* __restrict__ params, const float* __restrict__ xz,
    const float* __restrict__ A_log, const float* __restrict__ D_param,
    const float* __restrict__ Sinit, u16* __restrict__ y16)
{
  __shared__ __align__(16) float Bs[CL][DS];     // 1KB
  __shared__ __align__(16) float Cs[CL][DS];     // 1KB
  const int flat = blockIdx.x*256 + threadIdx.x;
  const int h  = flat & 1;                       // state half
  const int ch = flat >> 1;
  const int d = ch & (DI-1);
  const int c = (ch >> 11) & (NC-1);
  const int b = ch >> 17;
  const size_t lbase = (size_t)b*LL + (size_t)c*CL;
  {
    const int t = threadIdx.x;
    if (t < CL*DS/4) {
      const int row = t >> 2, col4 = (t & 3)*4;
      *(float4*)&Bs[row][col4] = *(const float4*)(params + (lbase+row)*96 + DTR + col4);
    } else if (t >= 128 && t < 128 + CL*DS/4) {
      const int t2 = t - 128;
      const int row = t2 >> 2, col4 = (t2 & 3)*4;
      *(float4*)&Cs[row][col4] = *(const float4*)(params + (lbase+row)*96 + DTR + DS + col4);
    }
  }
  __syncthreads();
  float a[8];
  #pragma unroll
  for (int i = 0; i < 2; ++i) {
    const float4 al = *(const float4*)(A_log + d*DS + h*8 + i*4);
    a[i*4+0] = -expf(al.x); a[i*4+1] = -expf(al.y);
    a[i*4+2] = -expf(al.z); a[i*4+3] = -expf(al.w);
  }
  const float Dp = D_param[d];
  const float* dl = delta + lbase*DI + d;
  const float* uu = u     + lbase*DI + d;
  const float* zp = xz + lbase*(2*DI) + DI + d;
  u16* yo = y16 + lbase*DI + d;
  const size_t base = (((size_t)(b*DI + d))*NC + c)*DS + h*8;
  float s[8];
  {
    const float4 s0 = *(const float4*)(Sinit + base);
    const float4 s1 = *(const float4*)(Sinit + base + 4);
    s[0]=s0.x; s[1]=s0.y; s[2]=s0.z; s[3]=s0.w;
    s[4]=s1.x; s[5]=s1.y; s[6]=s1.z; s[7]=s1.w;
  }
  for (int l0 = 0; l0 < CL; l0 += 8) {
    float dtv[8], utv[8], zv[8];
    #pragma unroll
    for (int j = 0; j < 8; ++j) {
      dtv[j] = dl[(size_t)(l0+j)*DI];
      utv[j] = uu[(size_t)(l0+j)*DI];
      zv[j]  = zp[(size_t)(l0+j)*(2*DI)];
    }
    u16 yv[8];
    #pragma unroll
    for (int j = 0; j < 8; ++j) {
      const float dt = dtv[j];
      const float ut = utv[j];
      const float dtu = dt*ut;
      const float4 B0 = *(const float4*)&Bs[l0+j][h*8+0];
      const float4 B1 = *(const float4*)&Bs[l0+j][h*8+4];
      const float4 C0 = *(const float4*)&Cs[l0+j][h*8+0];
      const float4 C1 = *(const float4*)&Cs[l0+j][h*8+4];
      const float Bv[8] = {B0.x,B0.y,B0.z,B0.w, B1.x,B1.y,B1.z,B1.w};
      const float Cv[8] = {C0.x,C0.y,C0.z,C0.w, C1.x,C1.y,C1.z,C1.w};
      float part = 0.f;
      #pragma unroll
      for (int n = 0; n < 8; ++n) {
        s[n] = fmaf(__expf(dt*a[n]), s[n], dtu*Bv[n]);
        part = fmaf(s[n], Cv[n], part);
      }
      part += __shfl_xor(part, 1);               // pair-sum over state halves
      yv[j] = f2b((part + Dp*ut) * siluf_(zv[j]));
    }
    if (h == 0) {
      #pragma unroll
      for (int j = 0; j < 8; ++j)
        yo[(size_t)(l0+j)*DI] = yv[j];
    }
  }
}

extern "C" void kernel_launch(void* const* d_in, const int* in_sizes, int n_in,
                              void* d_out, int out_size, void* d_ws, size_t ws_size,
                              hipStream_t stream)
{
  const float* x      = (const float*)d_in[0];
  const float* W_in   = (const float*)d_in[1];
  const float* conv_w = (const float*)d_in[2];
  const float* conv_b = (const float*)d_in[3];
  const float* W_x    = (const float*)d_in[4];
  const float* W_dt   = (const float*)d_in[5];
  const float* b_dt   = (const float*)d_in[6];
  const float* W_out  = (const float*)d_in[7];
  const float* A_log  = (const float*)d_in[8];
  const float* D_par  = (const float*)d_in[9];
  float* out = (float*)d_out;

  float* xz     = (float*)d_ws;             // MM*4096 f32 (32MB)
  float* u      = xz + (size_t)MM*2*DI;     // MM*DI f32 (16MB)
  float* params = u  + (size_t)MM*DI;       // MM*96 f32 (0.75MB)
  float* delta  = params + (size_t)MM*96;   // MM*DI f32 (16MB)
  u16*  pool    = (u16*)(delta + (size_t)MM*DI);
  // G1 phase:
  u16* xb16 = pool;                          // 2048*1024 (4MB), dead after G1
  u16* Wi_t = (u16*)out;                     // 4096*1024 bf16 = 8MB, in d_out
  // post-G1 phase (reuses pool):
  u16* Wo_t   = pool;                        // 1024*2048 bf16 (4MB)
  u16* yb16   = pool + (size_t)DM*DI;        // 2048*2048 bf16 (8MB)
  // NC=64 scan summaries: dedicated buffers in spare workspace (ws ~256MB)
  float* scanbuf = (float*)(yb16 + (size_t)MM*DI);
  const size_t PFN = (size_t)NB*DI*NC*DS;    // 4.19M floats (16.8MB) each
  float* Pc = scanbuf;                       // becomes Sinit after combine
  float* Fc = scanbuf + PFN;
  // d_out staging (dead before the final reduce writes out):
  float* xpart = out;                        // [8][2048][96] f32 = 6.3MB (after G1)
  // G4 split-K partials in xz region (dead after scan_apply): 4*MM*DM*4B = 32MB
  float* g4part = xz;

  dim3 blk(256);
  dim3 blk512(512);
  // convert x -> bf16; transpose-convert W_in -> [4096][1024] bf16 (in d_out)
  cvt_bf16_kern<<<(MM*DM/4 + 255)/256, blk, 0, stream>>>(x, DM, DM, xb16, MM);
  transpose_cvt_kern<<<dim3(2*DI/32, DM/32), blk, 0, stream>>>(W_in, Wi_t, DM, 2*DI);
  // G1: xz = x @ W_in   [2048 x 4096, K=1024]  (MFMA, 8-wave)
  gemm_mfma_kern<<<512, blk512, 0, stream>>>(xb16, Wi_t, xz, MM, 2*DI, DM, DM, 32, 16);
  // conv + silu -> u  (last reader of the xb-half of xz)
  conv_silu_kern<<<(MM*DI/4)/256, blk, 0, stream>>>(xz, conv_w, conv_b, u);
  // G2: params = u @ W_x  [2048 x 96, K=2048]  (fp32, K-split + reduce)
  xproj_part_kern<<<64*XSPLIT, blk, 0, stream>>>(u, W_x, xpart);
  xproj_reduce_kern<<<(MM*96/4)/256, blk, 0, stream>>>(xpart, params);
  // G3: delta = softplus(dlt @ W_dt + b_dt)  [2048 x 2048, K=64]  (fp32 one-pass)
  dtproj_kern<<<1024, blk, 0, stream>>>(params, W_dt, b_dt, delta);
  // chunked scan, NC=64, 2 lanes/channel (y written as bf16 to yb16)
  scan_local_kern<<<(NB*NC*DI*2)/256, blk, 0, stream>>>(delta, u, params, A_log, Pc, Fc);
  scan_combine_kern<<<(NB*DI*DS)/256, blk, 0, stream>>>(Pc, Fc);
  scan_apply_kern<<<(NB*NC*DI*2)/256, blk, 0, stream>>>(delta, u, params, xz, A_log, D_par, Pc, yb16);
  // G4: out = y @ W_out  [2048 x 1024, K=2048]  (MFMA, 8-wave, split-K=4 -> reduce)
  transpose_cvt_kern<<<dim3(DM/32, DI/32), blk, 0, stream>>>(W_out, Wo_t, DI, DM);
  gemm_mfma_kern<<<512, blk512, 0, stream>>>(yb16, Wo_t, g4part, MM, DM, DI, DI/4, 8, 16);
  reduce4_kern<<<(MM*DM/4)/256, blk, 0, stream>>>(g4part, out);
}

// Round 20
// 177.695 us; speedup vs baseline: 1.2013x; 1.0183x over previous
//
#include <hip/hip_runtime.h>
#include <hip/hip_bf16.h>
#include <math.h>

#define DM 1024
#define DI 2048
#define DS 16
#define DTR 64
#define NB 2
#define LL 1024
#define MM (NB*LL)   // 2048
#define NC 64        // scan chunks
#define CL (LL/NC)   // 16
#define XSPLIT 8
#define XKC (DI/XSPLIT)  // 256

typedef unsigned short u16;
typedef __bf16 bf16x8 __attribute__((ext_vector_type(8)));
typedef float f32x4 __attribute__((ext_vector_type(4)));
typedef const __attribute__((address_space(1))) void gas_void;
typedef __attribute__((address_space(3))) void las_void;

__device__ __forceinline__ float sigmoidf_(float x){ return 1.f/(1.f+__expf(-x)); }
__device__ __forceinline__ float siluf_(float x){ return x*sigmoidf_(x); }
__device__ __forceinline__ float softplusf_(float x){ return fmaxf(x,0.f)+__logf(1.f+__expf(-fabsf(x))); }
__device__ __forceinline__ u16 f2b(float f){
  __hip_bfloat16 h = __float2bfloat16(f);
  return __builtin_bit_cast(unsigned short, h);
}
__device__ __forceinline__ float b2f(u16 v){
  unsigned u = ((unsigned)v) << 16;
  return __builtin_bit_cast(float, u);
}
// CK-style: LDS generic VA low 32 bits = LDS offset; AS(3) ptr is 32-bit.
__device__ __forceinline__ void gld16(const u16* g, u16* l){
  __builtin_amdgcn_global_load_lds(
      reinterpret_cast<gas_void*>((unsigned long long)g),
      reinterpret_cast<las_void*>((unsigned)(unsigned long long)l), 16, 0, 0);
}

// ---------------- bf16 MFMA GEMM, 8-wave 128x128 tile ----------------
// OUTBF=0: f32 C; OUTBF=1: bf16 C (for split-K partials).
template<int OUTBF>
__global__ __launch_bounds__(512) void gemm_mfma_kern(
    const u16* __restrict__ A, const u16* __restrict__ Bt,
    void* __restrict__ Cv, int M, int N, int lda, int KS, int TN, int TM)
{
  __shared__ __attribute__((aligned(16))) u16 As[128*32];
  __shared__ __attribute__((aligned(16))) u16 Bs[128*32];
  const unsigned t = threadIdx.x;              // 0..511
  const unsigned l = t & 63;
  const unsigned w = t >> 6;                   // 0..7
  const unsigned wm = w >> 2, wn = w & 3;      // 2x4 wave grid, 64x32 each
  const int q8  = (int)gridDim.x >> 3;
  const int id2 = ((int)blockIdx.x & 7) * q8 + ((int)blockIdx.x >> 3);
  const int zz  = id2 / (TN*TM);
  const int rr  = id2 % (TN*TM);
  const int bm  = (rr / TN) * 128;
  const int bn  = (rr % TN) * 128;
  const int kbeg = zz * KS;
  const unsigned srow = t >> 2;                // 0..127
  const unsigned scol = (t & 3) * 8;
  f32x4 acc[4][2] = {};
  for (int k0 = kbeg; k0 < kbeg + KS; k0 += 32) {
    gld16(A  + (size_t)(bm + srow)*lda + k0 + scol, As + t*8);
    gld16(Bt + (size_t)(bn + srow)*lda + k0 + scol, Bs + t*8);
    __syncthreads();
    bf16x8 af[4], bfr[2];
    #pragma unroll
    for (int m = 0; m < 4; ++m)
      af[m] = *(const bf16x8*)(As + (wm*64 + m*16 + (l & 15))*32 + (l >> 4)*8);
    #pragma unroll
    for (int n = 0; n < 2; ++n)
      bfr[n] = *(const bf16x8*)(Bs + (wn*32 + n*16 + (l & 15))*32 + (l >> 4)*8);
    #pragma unroll
    for (int m = 0; m < 4; ++m)
      #pragma unroll
      for (int n = 0; n < 2; ++n)
        acc[m][n] = __builtin_amdgcn_mfma_f32_16x16x32_bf16(af[m], bfr[n], acc[m][n], 0, 0, 0);
    __syncthreads();
  }
  #pragma unroll
  for (int m = 0; m < 4; ++m) {
    #pragma unroll
    for (int n = 0; n < 2; ++n) {
      const int col = bn + wn*32 + n*16 + (l & 15);
      #pragma unroll
      for (int q = 0; q < 4; ++q) {
        const int row = bm + wm*64 + m*16 + (l >> 4)*4 + q;
        if (OUTBF) {
          u16* Cz = (u16*)Cv + (size_t)zz*M*N;
          Cz[(size_t)row*N + col] = f2b(acc[m][n][q]);
        } else {
          float* Cz = (float*)Cv + (size_t)zz*M*N;
          Cz[(size_t)row*N + col] = acc[m][n][q];
        }
      }
    }
  }
}

// fixed-order sum of 4 bf16 split-K partials (deterministic), f32 out
__global__ __launch_bounds__(256) void reduce4_kern(
    const u16* __restrict__ part, float* __restrict__ out)
{
  const size_t i = ((size_t)blockIdx.x*256 + threadIdx.x) * 4;
  float4 s = {0.f,0.f,0.f,0.f};
  #pragma unroll
  for (int ks = 0; ks < 4; ++ks) {
    const ushort4 v = *(const ushort4*)(part + (size_t)ks*MM*DM + i);
    s.x += b2f(v.x); s.y += b2f(v.y); s.z += b2f(v.z); s.w += b2f(v.w);
  }
  *(float4*)(out + i) = s;
}

// ---------------- dt-proj (G3), fp32 one-pass ----------------
__global__ __launch_bounds__(256) void dtproj_kern(
    const float* __restrict__ params, const float* __restrict__ W_dt,
    const float* __restrict__ b_dt, float* __restrict__ delta)
{
  __shared__ __align__(16) float Ad[32][DTR];    // 8KB
  __shared__ __align__(16) float Wd[DTR][128];   // 32KB
  const int tid = threadIdx.x;
  const int m0 = (blockIdx.x >> 4) * 32;
  const int c0 = (blockIdx.x & 15) * 128;
  #pragma unroll
  for (int i = 0; i < 2; ++i) {
    const int fq = i*256 + tid;
    const int r = fq >> 4, q = fq & 15;
    *(float4*)&Ad[r][q*4] = *(const float4*)(params + (size_t)(m0+r)*96 + q*4);
  }
  #pragma unroll
  for (int i = 0; i < 8; ++i) {
    const int fq = i*256 + tid;
    const int r = fq >> 5, q = fq & 31;
    *(float4*)&Wd[r][q*4] = *(const float4*)(W_dt + (size_t)r*DI + c0 + q*4);
  }
  __syncthreads();
  const int tr = tid >> 5;
  const int tc = tid & 31;
  f32x4 acc[4] = {};
  #pragma unroll
  for (int k0 = 0; k0 < DTR; k0 += 4) {
    float4 a[4], wv[4];
    #pragma unroll
    for (int i = 0; i < 4; ++i) a[i] = *(const float4*)&Ad[tr*4+i][k0];
    #pragma unroll
    for (int j = 0; j < 4; ++j) wv[j] = *(const float4*)&Wd[k0+j][tc*4];
    #pragma unroll
    for (int i = 0; i < 4; ++i) {
      const float ai[4] = {a[i].x, a[i].y, a[i].z, a[i].w};
      #pragma unroll
      for (int j = 0; j < 4; ++j) {
        acc[i][0] = fmaf(ai[j], wv[j].x, acc[i][0]);
        acc[i][1] = fmaf(ai[j], wv[j].y, acc[i][1]);
        acc[i][2] = fmaf(ai[j], wv[j].z, acc[i][2]);
        acc[i][3] = fmaf(ai[j], wv[j].w, acc[i][3]);
      }
    }
  }
  const float4 b4 = *(const float4*)(b_dt + c0 + tc*4);
  #pragma unroll
  for (int i = 0; i < 4; ++i) {
    float4 o;
    o.x = softplusf_(acc[i][0] + b4.x);
    o.y = softplusf_(acc[i][1] + b4.y);
    o.z = softplusf_(acc[i][2] + b4.z);
    o.w = softplusf_(acc[i][3] + b4.w);
    *(float4*)(delta + (size_t)(m0 + tr*4 + i)*DI + c0 + tc*4) = o;
  }
}

// transpose + convert: in [R][C] f32 -> out [C][R] bf16. grid(C/32, R/32).
__global__ __launch_bounds__(256) void transpose_cvt_kern(
    const float* __restrict__ in, u16* __restrict__ out, int R, int C)
{
  __shared__ float tile[32][33];
  const int r0 = blockIdx.y*32, c0 = blockIdx.x*32;
  const int tr = threadIdx.x >> 3, tc4 = (threadIdx.x & 7) * 4;
  float4 v = *(const float4*)(in + (size_t)(r0+tr)*C + c0 + tc4);
  tile[tr][tc4+0] = v.x; tile[tr][tc4+1] = v.y;
  tile[tr][tc4+2] = v.z; tile[tr][tc4+3] = v.w;
  __syncthreads();
  ushort4 o;
  o.x = f2b(tile[tc4+0][tr]);
  o.y = f2b(tile[tc4+1][tr]);
  o.z = f2b(tile[tc4+2][tr]);
  o.w = f2b(tile[tc4+3][tr]);
  *(ushort4*)(out + (size_t)(c0+tr)*R + r0 + tc4) = o;
}

// strided convert: out[row][0..C) bf16 = in[row*ld .. +C). C mult of 4.
__global__ __launch_bounds__(256) void cvt_bf16_kern(
    const float* __restrict__ in, int ld, int C, u16* __restrict__ out, int rows)
{
  const int i = blockIdx.x*256 + threadIdx.x;
  if (i >= rows*(C/4)) return;
  const int row = i / (C/4);
  const int cq  = (i % (C/4)) * 4;
  float4 v = *(const float4*)(in + (size_t)row*ld + cq);
  ushort4 o; o.x=f2b(v.x); o.y=f2b(v.y); o.z=f2b(v.z); o.w=f2b(v.w);
  *(ushort4*)(out + (size_t)row*C + cq) = o;
}

// ---------------- x-proj (G2), K-split fp32 ----------------
__global__ __launch_bounds__(256) void xproj_part_kern(
    const float* __restrict__ u, const float* __restrict__ W_x,
    float* __restrict__ part)
{
  __shared__ __align__(16) float Uk[XKC][32];   // 32KB, k-major
  const int tid = threadIdx.x;
  const int m0 = (blockIdx.x & 63) * 32;
  const int ks = blockIdx.x >> 6;
  const int k0 = ks * XKC;
  #pragma unroll
  for (int i = 0; i < 8; ++i) {
    const int fq = i*256 + tid;                  // 2048 float4s
    const int r = fq & 31, kq = fq >> 5;
    const float4 v = *(const float4*)(u + (size_t)(m0+r)*DI + k0 + kq*4);
    Uk[kq*4+0][r] = v.x; Uk[kq*4+1][r] = v.y;
    Uk[kq*4+2][r] = v.z; Uk[kq*4+3][r] = v.w;
  }
  __syncthreads();
  const int r4 = tid >> 5;                       // rows r4*4..+3
  const int c  = tid & 31;
  f32x4 a0 = {}, a1 = {}, a2 = {};
  #pragma unroll 4
  for (int k = 0; k < XKC; ++k) {
    const float* w = W_x + (size_t)(k0+k)*96 + c;
    const float w0 = w[0], w1 = w[32], w2 = w[64];
    const float4 uv = *(const float4*)&Uk[k][r4*4];
    const float ur[4] = {uv.x, uv.y, uv.z, uv.w};
    #pragma unroll
    for (int i = 0; i < 4; ++i) {
      a0[i] = fmaf(ur[i], w0, a0[i]);
      a1[i] = fmaf(ur[i], w1, a1[i]);
      a2[i] = fmaf(ur[i], w2, a2[i]);
    }
  }
  #pragma unroll
  for (int i = 0; i < 4; ++i) {
    float* p = part + ((size_t)ks*MM + m0 + r4*4 + i)*96 + c;
    p[0] = a0[i]; p[32] = a1[i]; p[64] = a2[i];
  }
}

__global__ __launch_bounds__(256) void xproj_reduce_kern(
    const float* __restrict__ part, float* __restrict__ params)
{
  const int i = blockIdx.x*256 + threadIdx.x;
  float4 s = {0.f,0.f,0.f,0.f};
  #pragma unroll
  for (int ks = 0; ks < XSPLIT; ++ks) {
    float4 v = *(const float4*)(part + (size_t)ks*MM*96 + (size_t)i*4);
    s.x+=v.x; s.y+=v.y; s.z+=v.z; s.w+=v.w;
  }
  *(float4*)(params + (size_t)i*4) = s;
}

// Causal depthwise conv (D_CONV=4) + SiLU, float4 over d (4 channels/thread).
__global__ __launch_bounds__(256) void conv_silu_kern(
    const float* __restrict__ xz, const float* __restrict__ conv_w,
    const float* __restrict__ conv_b, float* __restrict__ u)
{
  const int idx = blockIdx.x * 256 + threadIdx.x;   // over MM*DI/4
  const int d4 = (idx & (DI/4 - 1)) * 4;
  const int ml = idx >> 9;
  const int l  = ml & (LL-1);
  const int base = ml - l;
  const float4 w0 = *(const float4*)(conv_w + (d4+0)*4);
  const float4 w1 = *(const float4*)(conv_w + (d4+1)*4);
  const float4 w2 = *(const float4*)(conv_w + (d4+2)*4);
  const float4 w3 = *(const float4*)(conv_w + (d4+3)*4);
  const float wt[4][4] = {{w0.x,w0.y,w0.z,w0.w},{w1.x,w1.y,w1.z,w1.w},
                          {w2.x,w2.y,w2.z,w2.w},{w3.x,w3.y,w3.z,w3.w}};
  float4 acc = *(const float4*)(conv_b + d4);
  #pragma unroll
  for (int j = 0; j < 4; ++j) {
    const int ls = l - 3 + j;
    if (ls >= 0) {
      const float4 v = *(const float4*)(xz + (size_t)(base + ls)*(2*DI) + d4);
      acc.x = fmaf(v.x, wt[0][j], acc.x);
      acc.y = fmaf(v.y, wt[1][j], acc.y);
      acc.z = fmaf(v.z, wt[2][j], acc.z);
      acc.w = fmaf(v.w, wt[3][j], acc.w);
    }
  }
  float4 o;
  o.x = siluf_(acc.x); o.y = siluf_(acc.y);
  o.z = siluf_(acc.z); o.w = siluf_(acc.w);
  *(float4*)(u + (size_t)idx*4) = o;
}

// ---- chunk-parallel selective scan: 2 lanes/channel, 8 states/lane, NC=64 ----
__global__ __launch_bounds__(256) void scan_local_kern(
    const float* __restrict__ delta, const float* __restrict__ u,
    const float* __restrict__ params, const float* __restrict__ A_log,
    float* __restrict__ Pc, float* __restrict__ Fc)
{
  __shared__ __align__(16) float Bs[CL][DS];     // 1KB
  const int flat = blockIdx.x*256 + threadIdx.x;
  const int h  = flat & 1;                       // state half: n = h*8..h*8+7
  const int ch = flat >> 1;
  const int d = ch & (DI-1);
  const int c = (ch >> 11) & (NC-1);
  const int b = ch >> 17;
  const size_t lbase = (size_t)b*LL + (size_t)c*CL;
  if (threadIdx.x < CL*DS/4) {                   // 64 float4s
    const int row = threadIdx.x >> 2, col4 = (threadIdx.x & 3)*4;
    *(float4*)&Bs[row][col4] = *(const float4*)(params + (lbase+row)*96 + DTR + col4);
  }
  __syncthreads();
  float a[8];
  #pragma unroll
  for (int i = 0; i < 2; ++i) {
    const float4 al = *(const float4*)(A_log + d*DS + h*8 + i*4);
    a[i*4+0] = -expf(al.x); a[i*4+1] = -expf(al.y);
    a[i*4+2] = -expf(al.z); a[i*4+3] = -expf(al.w);
  }
  const float* dl = delta + lbase*DI + d;
  const float* uu = u     + lbase*DI + d;
  float s[8];
  #pragma unroll
  for (int n = 0; n < 8; ++n) s[n] = 0.f;
  float dtsum = 0.f;
  for (int l0 = 0; l0 < CL; l0 += 8) {
    float dtv[8], utv[8];
    #pragma unroll
    for (int j = 0; j < 8; ++j) {
      dtv[j] = dl[(size_t)(l0+j)*DI];
      utv[j] = uu[(size_t)(l0+j)*DI];
    }
    #pragma unroll
    for (int j = 0; j < 8; ++j) {
      const float dt = dtv[j];
      const float dtu = dt*utv[j];
      dtsum += dt;
      const float4 B0 = *(const float4*)&Bs[l0+j][h*8+0];
      const float4 B1 = *(const float4*)&Bs[l0+j][h*8+4];
      const float Bv[8] = {B0.x,B0.y,B0.z,B0.w, B1.x,B1.y,B1.z,B1.w};
      #pragma unroll
      for (int n = 0; n < 8; ++n)
        s[n] = fmaf(__expf(dt*a[n]), s[n], dtu*Bv[n]);
    }
  }
  const size_t base = (((size_t)(b*DI + d))*NC + c)*DS + h*8;
  float4 P0, P1;
  P0.x = __expf(dtsum*a[0]); P0.y = __expf(dtsum*a[1]);
  P0.z = __expf(dtsum*a[2]); P0.w = __expf(dtsum*a[3]);
  P1.x = __expf(dtsum*a[4]); P1.y = __expf(dtsum*a[5]);
  P1.z = __expf(dtsum*a[6]); P1.w = __expf(dtsum*a[7]);
  *(float4*)(Pc + base)     = P0;
  *(float4*)(Pc + base + 4) = P1;
  *(float4*)(Fc + base)     = make_float4(s[0],s[1],s[2],s[3]);
  *(float4*)(Fc + base + 4) = make_float4(s[4],s[5],s[6],s[7]);
}

// Combine: per (b,d,n), sequential over NC chunks. PS = Pc-in / Sinit-out.
__global__ __launch_bounds__(256) void scan_combine_kern(
    float* __restrict__ PS, const float* __restrict__ Fc)
{
  const int idx = blockIdx.x*256 + threadIdx.x;   // over NB*DI*DS
  const size_t base = (size_t)(idx >> 4) * (NC*DS) + (idx & 15);
  float s = 0.f;
  #pragma unroll
  for (int c = 0; c < NC; ++c) {
    const size_t a = base + (size_t)c*DS;
    const float P = PS[a], F = Fc[a];
    PS[a] = s;
    s = fmaf(P, s, F);
  }
}

// Pass B: rescan chunk from Sinit; fused C-dot + D*u + silu(z) gate -> y bf16.
__global__ __launch_bounds__(256) void scan_apply_kern(
    const float* __restrict__ delta, const float* __restrict__ u,
    const float* __restrict__ params, const float* __restrict__ xz,
    const float* __restrict__ A_log, const float* __restrict__ D_param,
    const float* __restrict__ Sinit, u16* __restrict__ y16)
{
  __shared__ __align__(16) float Bs[CL][DS];     // 1KB
  __shared__ __align__(16) float Cs[CL][DS];     // 1KB
  const int flat = blockIdx.x*256 + threadIdx.x;
  const int h  = flat & 1;                       // state half
  const int ch = flat >> 1;
  const int d = ch & (DI-1);
  const int c = (ch >> 11) & (NC-1);
  const int b = ch >> 17;
  const size_t lbase = (size_t)b*LL + (size_t)c*CL;
  {
    const int t = threadIdx.x;
    if (t < CL*DS/4) {
      const int row = t >> 2, col4 = (t & 3)*4;
      *(float4*)&Bs[row][col4] = *(const float4*)(params + (lbase+row)*96 + DTR + col4);
    } else if (t >= 128 && t < 128 + CL*DS/4) {
      const int t2 = t - 128;
      const int row = t2 >> 2, col4 = (t2 & 3)*4;
      *(float4*)&Cs[row][col4] = *(const float4*)(params + (lbase+row)*96 + DTR + DS + col4);
    }
  }
  __syncthreads();
  float a[8];
  #pragma unroll
  for (int i = 0; i < 2; ++i) {
    const float4 al = *(const float4*)(A_log + d*DS + h*8 + i*4);
    a[i*4+0] = -expf(al.x); a[i*4+1] = -expf(al.y);
    a[i*4+2] = -expf(al.z); a[i*4+3] = -expf(al.w);
  }
  const float Dp = D_param[d];
  const float* dl = delta + lbase*DI + d;
  const float* uu = u     + lbase*DI + d;
  const float* zp = xz + lbase*(2*DI) + DI + d;
  u16* yo = y16 + lbase*DI + d;
  const size_t base = (((size_t)(b*DI + d))*NC + c)*DS + h*8;
  float s[8];
  {
    const float4 s0 = *(const float4*)(Sinit + base);
    const float4 s1 = *(const float4*)(Sinit + base + 4);
    s[0]=s0.x; s[1]=s0.y; s[2]=s0.z; s[3]=s0.w;
    s[4]=s1.x; s[5]=s1.y; s[6]=s1.z; s[7]=s1.w;
  }
  for (int l0 = 0; l0 < CL; l0 += 8) {
    float dtv[8], utv[8], zv[8];
    #pragma unroll
    for (int j = 0; j < 8; ++j) {
      dtv[j] = dl[(size_t)(l0+j)*DI];
      utv[j] = uu[(size_t)(l0+j)*DI];
      zv[j]  = zp[(size_t)(l0+j)*(2*DI)];
    }
    u16 yv[8];
    #pragma unroll
    for (int j = 0; j < 8; ++j) {
      const float dt = dtv[j];
      const float ut = utv[j];
      const float dtu = dt*ut;
      const float4 B0 = *(const float4*)&Bs[l0+j][h*8+0];
      const float4 B1 = *(const float4*)&Bs[l0+j][h*8+4];
      const float4 C0 = *(const float4*)&Cs[l0+j][h*8+0];
      const float4 C1 = *(const float4*)&Cs[l0+j][h*8+4];
      const float Bv[8] = {B0.x,B0.y,B0.z,B0.w, B1.x,B1.y,B1.z,B1.w};
      const float Cv[8] = {C0.x,C0.y,C0.z,C0.w, C1.x,C1.y,C1.z,C1.w};
      float part = 0.f;
      #pragma unroll
      for (int n = 0; n < 8; ++n) {
        s[n] = fmaf(__expf(dt*a[n]), s[n], dtu*Bv[n]);
        part = fmaf(s[n], Cv[n], part);
      }
      part += __shfl_xor(part, 1);               // pair-sum over state halves
      yv[j] = f2b((part + Dp*ut) * siluf_(zv[j]));
    }
    if (h == 0) {
      #pragma unroll
      for (int j = 0; j < 8; ++j)
        yo[(size_t)(l0+j)*DI] = yv[j];
    }
  }
}

extern "C" void kernel_launch(void* const* d_in, const int* in_sizes, int n_in,
                              void* d_out, int out_size, void* d_ws, size_t ws_size,
                              hipStream_t stream)
{
  const float* x      = (const float*)d_in[0];
  const float* W_in   = (const float*)d_in[1];
  const float* conv_w = (const float*)d_in[2];
  const float* conv_b = (const float*)d_in[3];
  const float* W_x    = (const float*)d_in[4];
  const float* W_dt   = (const float*)d_in[5];
  const float* b_dt   = (const float*)d_in[6];
  const float* W_out  = (const float*)d_in[7];
  const float* A_log  = (const float*)d_in[8];
  const float* D_par  = (const float*)d_in[9];
  float* out = (float*)d_out;

  float* xz     = (float*)d_ws;             // MM*4096 f32 (32MB)
  float* u      = xz + (size_t)MM*2*DI;     // MM*DI f32 (16MB)
  float* params = u  + (size_t)MM*DI;       // MM*96 f32 (0.75MB)
  float* delta  = params + (size_t)MM*96;   // MM*DI f32 (16MB)
  u16*  pool    = (u16*)(delta + (size_t)MM*DI);
  // G1 phase:
  u16* xb16 = pool;                          // 2048*1024 (4MB), dead after G1
  u16* Wi_t = (u16*)out;                     // 4096*1024 bf16 = 8MB, in d_out
  // post-G1 phase (reuses pool):
  u16* Wo_t   = pool;                        // 1024*2048 bf16 (4MB)
  u16* yb16   = pool + (size_t)DM*DI;        // 2048*2048 bf16 (8MB)
  // NC=64 scan summaries: dedicated buffers in spare workspace (ws ~256MB)
  float* scanbuf = (float*)(yb16 + (size_t)MM*DI);
  const size_t PFN = (size_t)NB*DI*NC*DS;    // 4.19M floats (16.8MB) each
  float* Pc = scanbuf;                       // becomes Sinit after combine
  float* Fc = scanbuf + PFN;
  // d_out staging (dead before the final reduce writes out):
  float* xpart = out;                        // [8][2048][96] f32 = 6.3MB (after G1)
  // G4 split-K partials (bf16) overlay xz (fully dead after scan): 4*MM*DM*2B = 16MB
  u16* g4part = (u16*)xz;

  dim3 blk(256);
  dim3 blk512(512);
  // convert x -> bf16; transpose-convert W_in -> [4096][1024] bf16 (in d_out)
  cvt_bf16_kern<<<(MM*DM/4 + 255)/256, blk, 0, stream>>>(x, DM, DM, xb16, MM);
  transpose_cvt_kern<<<dim3(2*DI/32, DM/32), blk, 0, stream>>>(W_in, Wi_t, DM, 2*DI);
  // G1: xz = x @ W_in   [2048 x 4096, K=1024]  (MFMA, 8-wave, f32 out)
  gemm_mfma_kern<0><<<512, blk512, 0, stream>>>(xb16, Wi_t, xz, MM, 2*DI, DM, DM, 32, 16);
  // conv + silu -> u  (last reader of the xb-half of xz)
  conv_silu_kern<<<(MM*DI/4)/256, blk, 0, stream>>>(xz, conv_w, conv_b, u);
  // G2: params = u @ W_x  [2048 x 96, K=2048]  (fp32, K-split + reduce)
  xproj_part_kern<<<64*XSPLIT, blk, 0, stream>>>(u, W_x, xpart);
  xproj_reduce_kern<<<(MM*96/4)/256, blk, 0, stream>>>(xpart, params);
  // G3: delta = softplus(dlt @ W_dt + b_dt)  [2048 x 2048, K=64]  (fp32 one-pass)
  dtproj_kern<<<1024, blk, 0, stream>>>(params, W_dt, b_dt, delta);
  // chunked scan, NC=64, 2 lanes/channel (y written as bf16 to yb16)
  scan_local_kern<<<(NB*NC*DI*2)/256, blk, 0, stream>>>(delta, u, params, A_log, Pc, Fc);
  scan_combine_kern<<<(NB*DI*DS)/256, blk, 0, stream>>>(Pc, Fc);
  scan_apply_kern<<<(NB*NC*DI*2)/256, blk, 0, stream>>>(delta, u, params, xz, A_log, D_par, Pc, yb16);
  // G4: out = y @ W_out  [2048 x 1024, K=2048]  (MFMA, split-K=4, bf16 partials -> reduce)
  transpose_cvt_kern<<<dim3(DM/32, DI/32), blk, 0, stream>>>(W_out, Wo_t, DI, DM);
  gemm_mfma_kern<1><<<512, blk512, 0, stream>>>(yb16, Wo_t, g4part, MM, DM, DI, DI/4, 8, 16);
  reduce4_kern<<<(MM*DM/4)/256, blk, 0, stream>>>(g4part, out);
}